// Round 10
// baseline (277.287 us; speedup 1.0000x reference)
//
#include <hip/hip_runtime.h>
#include <stdint.h>

// sample_and_group: B=8 N=8192 C=64 S=2048 K=32 OUT=128
// out = (out[8,2048,128], sampled_coor[8,2048,3]) concatenated in d_out (float32).
//
// R23: kphase occupancy 2 -> 3 blocks/CU (the largest remaining cost block,
// ~135-145us combined, is latency/sync bound at 2 waves/SIMD; arithmetic
// floors are ~6us so occupancy is the lever):
//  - launch_bounds (256,2) -> (256,3): 170 VGPR/wave.
//  - PHASE2: bf2 no longer persistent (32 regs freed -> peak ~120-140 < 170,
//    no spill risk per R17 lesson). Reloaded per group from w2b (32KB,
//    L2/L3-hot chip-wide) during the h1 pack; the pack + barrier covers L2
//    latency; values identical -> bit-exact.
//  - GPB 16 -> 8 (2048 blocks): 8 blocks/CU tiles 3-resident as 3+3+2 (89%)
//    vs 1024-block 3+1 (67%). kred1 back to 32 rows/block.
// kknn frozen at its best-measured form (R22: 83.3us; VALUBusy 68%; further
// selection micro-opts are inside the +/-5-9us run noise band).
//
// Workspace layout (bytes):
//   [0,2MB)        knn indices  int32[16384*32]
//   [2MB,10MB)     m = max_k y2 f32[16384*128]
//   [10MB,11MB)    soa coords  f32[8][3][8192] (ALIASES part1; kknn-only lifetime)
//   [10MB,12MB)    partials1    f32[2048*256]
//   [12MB,14MB)    partials2    f32[2048*256]
//   [14MB,+32KB)   w1b  bf16 [o][k=0..127]
//   [..,+32KB)     w2b  bf16 [o][k=0..127]
//   [..,+1KB)      stats1 (scale[128], shift[128])
//   [..,+1KB)      stats2
//   [..,+128KB)    dbuf f64[64*256] (reduce stage-1 output)

#define N_    8192
#define GPB_  8       // groups per block in phase kernels

typedef __attribute__((ext_vector_type(8))) short bf8;
typedef __attribute__((ext_vector_type(16))) float f32x16;
typedef __attribute__((ext_vector_type(2))) float f32x2;

__device__ __forceinline__ unsigned int bf1u(float f) {   // RNE fp32->bf16 bits
  unsigned int u = __float_as_uint(f);
  return (u + 0x7fffu + ((u >> 16) & 1u)) >> 16;
}
__device__ __forceinline__ unsigned int bfpair(float lo, float hi) {
  return bf1u(lo) | (bf1u(hi) << 16);
}

// packed fp32 VOP3P helpers (CDNA: 2x fp32 per instruction, IEEE RN per lane)
__device__ __forceinline__ f32x2 pk_add(f32x2 a, f32x2 b) {
  f32x2 d;
  asm("v_pk_add_f32 %0, %1, %2" : "=v"(d) : "v"(a), "v"(b));
  return d;
}
__device__ __forceinline__ f32x2 pk_mul(f32x2 a, f32x2 b) {
  f32x2 d;
  asm("v_pk_mul_f32 %0, %1, %2" : "=v"(d) : "v"(a), "v"(b));
  return d;
}

// ---------------- prep: weight layouts + SoA coord pack + sampled_coor -------
__global__ __launch_bounds__(256) void kprep(const float* __restrict__ w1,
                                             const float* __restrict__ w2,
                                             const float* __restrict__ coor,
                                             const int* __restrict__ indx,
                                             unsigned short* __restrict__ w1b,
                                             unsigned short* __restrict__ w2b,
                                             float* __restrict__ outc,
                                             float* __restrict__ soa) {
  int e = blockIdx.x * 256 + threadIdx.x;   // grid is exactly 576*256 = 147456
  if (e < 16384) {                           // w1b[o][k] = bf16(w1[o][k])
    w1b[e] = (unsigned short)bf1u(w1[e]);
  } else if (e < 32768) {                    // w2b[o][k] = bf16(w2[o][k])
    int e2 = e - 16384;
    w2b[e2] = (unsigned short)bf1u(w2[e2]);
  } else if (e < 81920) {
    int e2 = e - 32768;                      // 0..49151 sampled_coor
    int bs = e2 / 3, c = e2 - bs * 3;
    int b = bs >> 11, s = bs & 2047;
    outc[e2] = coor[(b * N_ + indx[s]) * 3 + c];
  } else {
    int p = e - 81920;                       // 0..65535 SoA pack
    const int b = p >> 13, i = p & 8191;
    const float* src = coor + (size_t)p * 3;
    float* dst = soa + b * 24576;
    dst[i]         = src[0];
    dst[8192 + i]  = src[1];
    dst[16384 + i] = src[2];
  }
}

// ---------------- KNN: threshold-select, one query per 256-thread block -------
// Output = SET of 32 smallest keys (dist_bits<<32 | idx); order arbitrary
// (downstream max/mean/var are permutation-invariant over K).
// dist[macro 0..3] in registers, macro 4..7 in LDS; NO recompute.
__global__ __launch_bounds__(256, 8) void kknn(const float* __restrict__ soa,
                                               const int* __restrict__ indx,
                                               int* __restrict__ knn) {
  __shared__ __align__(16) float4 sdist4[4 * 256];  // 16KB: dist[it-4][tid] x4
  __shared__ float sTw[8];                    // per-half-wave 4th-smallest min
  __shared__ unsigned long long cands[192];
  __shared__ int ccnt;

  const int gid = blockIdx.x;
  const int b = gid >> 11, s = gid & 2047;
  const int tid = threadIdx.x;
  const int w = tid >> 6, lane = tid & 63;
  const int hl = lane & 31;                   // half-wave lane
  const float* Xb = soa + b * 24576;
  const float* Yb = Xb + 8192;
  const float* Zb = Xb + 16384;
  const int qi = indx[s];
  const float qx = Xb[qi], qy = Yb[qi], qz = Zb[qi];
  const f32x2 nqx = {-qx, -qx}, nqy = {-qy, -qy}, nqz = {-qz, -qz};

  // pass 1: 8 macro-iters x 4 adjacent points per lane (packed fp32 math).
  // Per component: d = ((dx*dx + dy*dy) + dz*dz), dx = cx + (-qx) -- bit-exact
  // vs scalar __fsub_rn/__fmul_rn/__fadd_rn.
  f32x2 rd[8];                                // macro 0..3 -> 16 dists in regs
  float dmA = 3.4e38f, dmB = 3.4e38f;
#pragma unroll
  for (int it = 0; it < 8; ++it) {
    const int ofs = (it << 10) + (tid << 2);
    union { float4 f4; f32x2 h[2]; } X, Y, Z;
    X.f4 = *(const float4*)(Xb + ofs);
    Y.f4 = *(const float4*)(Yb + ofs);
    Z.f4 = *(const float4*)(Zb + ofs);
    const f32x2 dxl = pk_add(X.h[0], nqx), dyl = pk_add(Y.h[0], nqy),
                dzl = pk_add(Z.h[0], nqz);
    const f32x2 dxh = pk_add(X.h[1], nqx), dyh = pk_add(Y.h[1], nqy),
                dzh = pk_add(Z.h[1], nqz);
    const f32x2 sl =
        pk_add(pk_add(pk_mul(dxl, dxl), pk_mul(dyl, dyl)), pk_mul(dzl, dzl));
    const f32x2 sh =
        pk_add(pk_add(pk_mul(dxh, dxh), pk_mul(dyh, dyh)), pk_mul(dzh, dzh));
    dmA = fminf(fminf(sl.x, sl.y), dmA);      // v_min3_f32
    dmB = fminf(fminf(sh.x, sh.y), dmB);
    if (it < 4) {
      rd[it * 2] = sl;
      rd[it * 2 + 1] = sh;
    } else {
      union { float4 f4; f32x2 h[2]; } st;
      st.h[0] = sl;
      st.h[1] = sh;
      sdist4[((it - 4) << 8) + tid] = st.f4;   // one ds_write_b128
    }
  }
  float dmin = fminf(dmA, dmB);
  if (tid == 0) ccnt = 0;
  if (tid < 192) cands[tid] = ~0ULL;          // sentinel (> any real key)

  // pass 2: per-HALF-WAVE ascending bitonic sort (32 elements, 15 stages;
  // direction from hl=lane&31 so both halves sort ascending). Lane hl==3
  // holds the half-wave's 4th-smallest thread-min. T = max over the 8
  // half-waves. Each half-wave has >=4 thread-mins <= T -> >=4 distinct
  // elements <= T -> >=32 total -> T >= d32.
  float v = dmin;
#pragma unroll
  for (int k = 2; k <= 32; k <<= 1) {
#pragma unroll
    for (int j = k >> 1; j >= 1; j >>= 1) {
      const float o = __shfl_xor(v, j, 64);
      const bool dirAsc = ((hl & k) == 0);
      const bool lower = ((hl & j) == 0);
      const float lo = fminf(v, o), hi = fmaxf(v, o);
      v = (dirAsc == lower) ? lo : hi;
    }
  }
  if (hl == 3) sTw[(w << 1) + (lane >> 5)] = v;
  __syncthreads();
  const float T =
      fmaxf(fmaxf(fmaxf(sTw[0], sTw[1]), fmaxf(sTw[2], sTw[3])),
            fmaxf(fmaxf(sTw[4], sTw[5]), fmaxf(sTw[6], sTw[7])));

  // pass 3: compact candidates (dist <= T) from regs + LDS; E~55-70, cap 192.
  // Sparse predicate -> per-lane atomicAdd is cheaper than wave aggregation
  // (R19 post-mortem).
#pragma unroll
  for (int t = 0; t < 8; ++t) {
    const int p0 = ((t >> 1) << 10) + (tid << 2) + ((t & 1) << 1);
    const float d0 = rd[t].x, d1 = rd[t].y;
    if (d0 <= T) {
      const int pos = atomicAdd(&ccnt, 1);
      if (pos < 192)
        cands[pos] = ((unsigned long long)__float_as_uint(d0) << 32) |
                     (unsigned int)p0;
    }
    if (d1 <= T) {
      const int pos = atomicAdd(&ccnt, 1);
      if (pos < 192)
        cands[pos] = ((unsigned long long)__float_as_uint(d1) << 32) |
                     (unsigned int)(p0 + 1);
    }
  }
#pragma unroll
  for (int it = 4; it < 8; ++it) {
    const float4 d4 = sdist4[((it - 4) << 8) + tid];   // one ds_read_b128
    const int p0 = (it << 10) + (tid << 2);
    const float dd[4] = {d4.x, d4.y, d4.z, d4.w};
#pragma unroll
    for (int j = 0; j < 4; ++j) {
      if (dd[j] <= T) {
        const int pos = atomicAdd(&ccnt, 1);
        if (pos < 192)
          cands[pos] = ((unsigned long long)__float_as_uint(dd[j]) << 32) |
                       (unsigned int)(p0 + j);
      }
    }
  }
  __syncthreads();

  // pass 4: exact top-32 of E candidates by rank-count. Keys distinct (idx in
  // low bits) -> ranks 0..E-1 a permutation; rank<32 writes. Scan padded to
  // Ep=(E+3)&~3 with unroll-4: slots [E,192) hold ~0ULL sentinels which never
  // compare < key (real keys < ~0ULL), so rank is exact while the broadcast
  // ds_reads batch 4 per waitcnt instead of dependent singles.
  const int E = min(ccnt, 192);               // E >= 32 guaranteed
  if (tid < E) {
    const unsigned long long key = cands[tid];
    int rank = 0;
    const int Ep = (E + 3) & ~3;
#pragma unroll 4
    for (int j = 0; j < Ep; ++j) rank += (cands[j] < key) ? 1 : 0;
    if (rank < 32) knn[gid * 32 + rank] = (int)(unsigned int)key;
  }
}

// ---------------- phase kernels: MFMA fused GEMMs ----------------------------
// Wave w owns cols 32w..32w+31. Per lane: m = lane&31 (A row / D col), q2 = lane>>5.
// A layout: A[m=lane&31][k=q2*8+j]; B layout: B^T[n=lane&31][k=q2*8+j];
// C/D layout: col=lane&31, row=(reg&3)+8*(reg>>2)+4*q2  [m74/m101-verified].
// Layer-1 is K=128: A = [sx bf16 (k<64) | d bf16 (k>=64)], B = full w1.
// XCD map: batch = blockIdx&7 (one 2MB x-slice per XCD L2).
// Pipeline: central row AND gather rows for g+1 prefetched into registers;
// raw s_barrier with lgkmcnt-only drain keeps those loads in flight.
// launch_bounds(256,3): 170 VGPR/wave, 3 blocks/CU (12 waves/CU). Phase2's
// bf2 reloaded per group from L2-hot w2b (frees 32 persistent regs -> fits).
template <int PHASE>
__global__ __launch_bounds__(256, 3) void kphase(
    const float* __restrict__ x, const int* __restrict__ indx,
    const int* __restrict__ knn, const float* __restrict__ b1,
    const unsigned short* __restrict__ w1b, const unsigned short* __restrict__ w2b,
    const float* __restrict__ b2, const float* __restrict__ st1,
    float* __restrict__ part, float* __restrict__ mout) {
  __shared__ __align__(16) unsigned short sxb[2][80];          // bf16 sx x2
  __shared__ __align__(16) unsigned short dls[2][32 * 68 + 8]; // d rows x2
  __shared__ __align__(16) unsigned short h1[PHASE == 2 ? 2 * 32 * 136 : 8];

  const int tid = threadIdx.x;
  const int w = tid >> 6;
  const int lane = tid & 63;
  const int m = lane & 31, q2 = lane >> 5;
  const int col = (w << 5) + m;              // output channel of this lane
  const int r8 = tid >> 3, c8 = (tid & 7) * 8;  // staging map: row, col-base

  const int bb = blockIdx.x & 7;             // batch == target XCD
  const int jj = blockIdx.x >> 3;            // 0..255 chunk within batch
  const float* xb = x + (size_t)bb * (N_ * 64);
  const int gidbase = (bb << 11) + jj * GPB_;
  const int sbase = jj * GPB_;

  // group-invariant operands in registers
  bf8 bf1[8];
#pragma unroll
  for (int t = 0; t < 8; ++t)
    bf1[t] = *(const bf8*)&w1b[col * 128 + t * 16 + q2 * 8];
  float s1 = 0.f, t1 = 0.f, b2v = 0.f;
  if constexpr (PHASE == 2) {
    s1 = st1[col];
    t1 = st1[128 + col];
    b2v = b2[col];
  }
  (void)w2b; (void)b2; (void)st1; (void)mout;
  const float b1c = b1[col];

  float sum = 0.f, ssq = 0.f;

  // pipeline prologue: central + gather rows for g=0 into regs; indices for g=1
  float4 ca_c, cc_c, ga_c, gc_c;
  {
    const int idx0 = indx[sbase];
    const int nbr0 = knn[(size_t)gidbase * 32 + r8];
    const float* c0 = xb + (size_t)idx0 * 64;
    ca_c = *(const float4*)(c0 + c8);
    cc_c = *(const float4*)(c0 + c8 + 4);
    const float* g0 = xb + (size_t)nbr0 * 64;
    ga_c = *(const float4*)(g0 + c8);
    gc_c = *(const float4*)(g0 + c8 + 4);
  }
  int idx_nxt = (GPB_ > 1) ? indx[sbase + 1] : 0;
  int nbr_nxt = (GPB_ > 1) ? knn[(size_t)(gidbase + 1) * 32 + r8] : 0;

#pragma unroll 1
  for (int g = 0; g < GPB_; ++g) {
    const int gid = gidbase + g;
    const int p = g & 1;

    // issue prefetch for g+1 rows FIRST (stays in flight across the barrier)
    float4 ca_n = ca_c, cc_n = cc_c, ga_n = ga_c, gc_n = gc_c;
    if (g + 1 < GPB_) {
      const float* cn = xb + (size_t)idx_nxt * 64;
      ca_n = *(const float4*)(cn + c8);
      cc_n = *(const float4*)(cn + c8 + 4);
      const float* gn = xb + (size_t)nbr_nxt * 64;
      ga_n = *(const float4*)(gn + c8);
      gc_n = *(const float4*)(gn + c8 + 4);
    }
    // indices for g+2 (consumed next iteration)
    if (g + 2 < GPB_) {
      nbr_nxt = knn[(size_t)(gid + 2) * 32 + r8];
      idx_nxt = indx[sbase + g + 2];
    }

    // stage d = x[nbr] - sx as bf16 into dls[p] (regs only; loaded last iter)
    {
      uint2 lo, hi;
      lo.x = bfpair(ga_c.x - ca_c.x, ga_c.y - ca_c.y);
      lo.y = bfpair(ga_c.z - ca_c.z, ga_c.w - ca_c.w);
      hi.x = bfpair(gc_c.x - cc_c.x, gc_c.y - cc_c.y);
      hi.y = bfpair(gc_c.z - cc_c.z, gc_c.w - cc_c.w);
      *(uint2*)&dls[p][r8 * 68 + c8] = lo;     // byte addr 136*r8+16k: 8B-aligned
      *(uint2*)&dls[p][r8 * 68 + c8 + 4] = hi;
    }
    if (tid < 8) {                             // tid<8: c8==tid*8 -> holds the
      uint2 lo, hi;                            // full central row in ca/cc
      lo.x = bfpair(ca_c.x, ca_c.y);
      lo.y = bfpair(ca_c.z, ca_c.w);
      hi.x = bfpair(cc_c.x, cc_c.y);
      hi.y = bfpair(cc_c.z, cc_c.w);
      *(uint2*)&sxb[p][tid * 8] = lo;
      *(uint2*)&sxb[p][tid * 8 + 4] = hi;
    }
    // LDS-visibility-only barrier: vmcnt NOT drained -> prefetch keeps flying
    asm volatile("s_waitcnt lgkmcnt(0)" ::: "memory");
    __builtin_amdgcn_s_barrier();

    // A-frags: t<4 from sxb[p] (k<64), t>=4 from dls[p] (k>=64)
    bf8 af[8];
#pragma unroll
    for (int t = 0; t < 4; ++t) {
      union { bf8 v; uint2 u[2]; } fa;
      fa.u[0] = *(const uint2*)&sxb[p][t * 16 + q2 * 8];
      fa.u[1] = *(const uint2*)&sxb[p][t * 16 + q2 * 8 + 4];
      af[t] = fa.v;
    }
#pragma unroll
    for (int t = 0; t < 4; ++t) {
      union { bf8 v; uint2 u[2]; } fa;
      fa.u[0] = *(const uint2*)&dls[p][m * 68 + t * 16 + q2 * 8];
      fa.u[1] = *(const uint2*)&dls[p][m * 68 + t * 16 + q2 * 8 + 4];
      af[4 + t] = fa.v;
    }

    f32x16 acc;
#pragma unroll
    for (int r = 0; r < 16; ++r) acc[r] = b1c;
#pragma unroll
    for (int t = 0; t < 8; ++t)
      acc = __builtin_amdgcn_mfma_f32_32x32x16_bf16(af[t], bf1[t], acc, 0, 0, 0);

    if constexpr (PHASE == 1) {
#pragma unroll
      for (int r = 0; r < 16; ++r) {
        const float v = acc[r];
        sum += v;
        ssq = fmaf(v, v, ssq);
      }
    } else {
      // bn1 + relu -> h1[p] bf16 in LDS (C-layout scatter, row stride 136)
      const int hp = p * (32 * 136);
#pragma unroll
      for (int r = 0; r < 16; ++r) {
        const float hv = fmaxf(0.f, fmaf(acc[r], s1, t1));
        const int row = (r & 3) + ((r >> 2) << 3) + (q2 << 2);
        h1[hp + row * 136 + col] = (unsigned short)bf1u(hv);
      }
      // bf2 fragments: reloaded per group from L2-hot w2b (group-invariant
      // values; issued here so the h1 pack + barrier covers L2 latency;
      // global loads are NOT drained by the lgkm-only barrier).
      bf8 bf2[8];
#pragma unroll
      for (int t = 0; t < 8; ++t)
        bf2[t] = *(const bf8*)&w2b[col * 128 + t * 16 + q2 * 8];
      asm volatile("s_waitcnt lgkmcnt(0)" ::: "memory");
      __builtin_amdgcn_s_barrier();            // h1[p] ready (lgkm only)

      f32x16 acc2;
#pragma unroll
      for (int r = 0; r < 16; ++r) acc2[r] = b2v;
#pragma unroll
      for (int t = 0; t < 8; ++t) {
        const bf8 a2 = *(const bf8*)&h1[hp + m * 136 + t * 16 + q2 * 8];
        acc2 = __builtin_amdgcn_mfma_f32_32x32x16_bf16(a2, bf2[t], acc2, 0, 0, 0);
      }

      float mx = -1e30f;
#pragma unroll
      for (int r = 0; r < 16; ++r) {
        const float v = acc2[r];
        sum += v;
        ssq = fmaf(v, v, ssq);
        mx = fmaxf(mx, v);
      }
      mx = fmaxf(mx, __shfl_xor(mx, 32, 64));
      if (lane < 32) mout[(size_t)gid * 128 + col] = mx;
    }

    // rotate prefetched rows
    ca_c = ca_n;
    cc_c = cc_n;
    ga_c = ga_n;
    gc_c = gc_n;
  }

  // channel partials: each channel owned by exactly one wave
  sum += __shfl_xor(sum, 32, 64);
  ssq += __shfl_xor(ssq, 32, 64);
  if (lane < 32) {
    part[blockIdx.x * 256 + col] = sum;
    part[blockIdx.x * 256 + 128 + col] = ssq;
  }
}

// ---------------- stats reduce stage 1: 64 blocks, f64 partial sums ----------
__global__ __launch_bounds__(256) void kred1(const float* __restrict__ part,
                                             double* __restrict__ dbuf) {
  const int blk = blockIdx.x;                // 0..63: rows 32*blk..32*blk+31
  const int c = threadIdx.x;                 // 0..255 (128 sums | 128 ssqs)
  const float* p = part + (size_t)blk * 32 * 256 + c;
  double acc = 0.0;
#pragma unroll 8
  for (int r = 0; r < 32; ++r) acc += (double)p[r * 256];
  dbuf[blk * 256 + c] = acc;
}

// ---------------- stats reduce stage 2: finalize scale/shift -----------------
__global__ __launch_bounds__(256) void kred2(const double* __restrict__ dbuf,
                                             const float* __restrict__ gam,
                                             const float* __restrict__ bet,
                                             float* __restrict__ st) {
  __shared__ double sS[256];
  const int c = threadIdx.x;
  double acc = 0.0;
#pragma unroll 8
  for (int i = 0; i < 64; ++i) acc += dbuf[i * 256 + c];
  sS[c] = acc;
  __syncthreads();
  if (c < 128) {
    const double Sv = sS[c], SSv = sS[128 + c];
    const double cnt = 524288.0;             // B*S*K
    const double mean = Sv / cnt;
    const double var = SSv / cnt - mean * mean;
    const double scale = (double)gam[c] / sqrt(var + 1e-5);
    st[c] = (float)scale;
    st[128 + c] = (float)((double)bet[c] - mean * scale);
  }
}

// ---------------- final: out = relu(scale2 * max_k(y2) + shift2) -------------
__global__ __launch_bounds__(256) void kout(const float* __restrict__ m,
                                            const float* __restrict__ st2,
                                            float* __restrict__ out) {
  const int e4 = blockIdx.x * 256 + threadIdx.x;  // 524288 float4s
  const int o0 = (e4 & 31) * 4;
  const float4 v = ((const float4*)m)[e4];
  const float4 sc = *(const float4*)&st2[o0];
  const float4 sh = *(const float4*)&st2[128 + o0];
  float4 r;
  r.x = fmaxf(0.f, fmaf(v.x, sc.x, sh.x));
  r.y = fmaxf(0.f, fmaf(v.y, sc.y, sh.y));
  r.z = fmaxf(0.f, fmaf(v.z, sc.z, sh.z));
  r.w = fmaxf(0.f, fmaf(v.w, sc.w, sh.w));
  ((float4*)out)[e4] = r;
}

extern "C" void kernel_launch(void* const* d_in, const int* in_sizes, int n_in,
                              void* d_out, int out_size, void* d_ws, size_t ws_size,
                              hipStream_t stream) {
  (void)in_sizes; (void)n_in; (void)out_size; (void)ws_size;
  const float* x    = (const float*)d_in[0];
  const float* coor = (const float*)d_in[1];
  const int*   indx = (const int*)d_in[2];
  const float* w1   = (const float*)d_in[3];
  const float* b1   = (const float*)d_in[4];
  const float* g1   = (const float*)d_in[5];
  const float* be1  = (const float*)d_in[6];
  const float* w2   = (const float*)d_in[7];
  const float* b2   = (const float*)d_in[8];
  const float* g2   = (const float*)d_in[9];
  const float* be2  = (const float*)d_in[10];
  float* out = (float*)d_out;

  char* ws = (char*)d_ws;
  int*            knn   = (int*)(ws + 0);
  float*          mbuf  = (float*)(ws + 2097152);
  float*          part1 = (float*)(ws + 10485760);
  float*          soa   = (float*)(ws + 10485760); // aliases part1 (disjoint lifetime)
  float*          part2 = (float*)(ws + 12582912);
  unsigned short* w1b   = (unsigned short*)(ws + 14680064);
  unsigned short* w2b   = (unsigned short*)(ws + 14712832);
  float*          st1   = (float*)(ws + 14745600);
  float*          st2   = (float*)(ws + 14746624);
  double*         dbuf  = (double*)(ws + 14747648);

  float* outc = out + 2097152;   // sampled_coor region of d_out

  kprep<<<576, 256, 0, stream>>>(w1, w2, coor, indx, w1b, w2b, outc, soa);
  kknn<<<16384, 256, 0, stream>>>(soa, indx, knn);
  kphase<1><<<2048, 256, 0, stream>>>(x, indx, knn, b1, w1b, w2b, b2, nullptr,
                                      part1, nullptr);
  kred1<<<64, 256, 0, stream>>>(part1, dbuf);
  kred2<<<1, 256, 0, stream>>>(dbuf, g1, be1, st1);
  kphase<2><<<2048, 256, 0, stream>>>(x, indx, knn, b1, w1b, w2b, b2, st1,
                                      part2, mbuf);
  kred1<<<64, 256, 0, stream>>>(part2, dbuf);
  kred2<<<1, 256, 0, stream>>>(dbuf, g2, be2, st2);
  kout<<<2048, 256, 0, stream>>>(mbuf, st2, out);
}

// Round 11
// 247.254 us; speedup vs baseline: 1.1215x; 1.1215x over previous
//
#include <hip/hip_runtime.h>
#include <stdint.h>

// sample_and_group: B=8 N=8192 C=64 S=2048 K=32 OUT=128
// out = (out[8,2048,128], sampled_coor[8,2048,3]) concatenated in d_out (float32).
//
// R24: revert R23 (confounded 3-way change; kphase2 87.7us, total 277).
// Baseline = R22 (measured best kphase config: GPB=16, persistent bf2,
// lgkm-only barriers, depth-1 reg prefetch). ONE new variable:
//   launch_bounds(256, PHASE==1 ? 3 : 2)
// Phase1 uses no bf2/acc2 (~130 regs peak < 170) -> 3 blocks/CU free of
// spill risk. Phase2 (~178 regs) stays at (256,2) per R17's spill lesson.
// Spill tripwire for the post-mortem: phase1 WRITE_SIZE must stay ~2MB.
//
// Workspace layout (bytes):
//   [0,2MB)        knn indices  int32[16384*32]
//   [2MB,10MB)     m = max_k y2 f32[16384*128]
//   [10MB,11MB)    soa coords  f32[8][3][8192] (ALIASES part1; kknn-only lifetime)
//   [10MB,12MB)    partials1    f32[1024*256]
//   [12MB,14MB)    partials2    f32[1024*256]
//   [14MB,+32KB)   w1b  bf16 [o][k=0..127]
//   [..,+32KB)     w2b  bf16 [o][k=0..127]
//   [..,+1KB)      stats1 (scale[128], shift[128])
//   [..,+1KB)      stats2
//   [..,+128KB)    dbuf f64[64*256] (reduce stage-1 output)

#define N_    8192
#define GPB_  16      // groups per block in phase kernels

typedef __attribute__((ext_vector_type(8))) short bf8;
typedef __attribute__((ext_vector_type(16))) float f32x16;
typedef __attribute__((ext_vector_type(2))) float f32x2;

__device__ __forceinline__ unsigned int bf1u(float f) {   // RNE fp32->bf16 bits
  unsigned int u = __float_as_uint(f);
  return (u + 0x7fffu + ((u >> 16) & 1u)) >> 16;
}
__device__ __forceinline__ unsigned int bfpair(float lo, float hi) {
  return bf1u(lo) | (bf1u(hi) << 16);
}

// packed fp32 VOP3P helpers (CDNA: 2x fp32 per instruction, IEEE RN per lane)
__device__ __forceinline__ f32x2 pk_add(f32x2 a, f32x2 b) {
  f32x2 d;
  asm("v_pk_add_f32 %0, %1, %2" : "=v"(d) : "v"(a), "v"(b));
  return d;
}
__device__ __forceinline__ f32x2 pk_mul(f32x2 a, f32x2 b) {
  f32x2 d;
  asm("v_pk_mul_f32 %0, %1, %2" : "=v"(d) : "v"(a), "v"(b));
  return d;
}

// ---------------- prep: weight layouts + SoA coord pack + sampled_coor -------
__global__ __launch_bounds__(256) void kprep(const float* __restrict__ w1,
                                             const float* __restrict__ w2,
                                             const float* __restrict__ coor,
                                             const int* __restrict__ indx,
                                             unsigned short* __restrict__ w1b,
                                             unsigned short* __restrict__ w2b,
                                             float* __restrict__ outc,
                                             float* __restrict__ soa) {
  int e = blockIdx.x * 256 + threadIdx.x;   // grid is exactly 576*256 = 147456
  if (e < 16384) {                           // w1b[o][k] = bf16(w1[o][k])
    w1b[e] = (unsigned short)bf1u(w1[e]);
  } else if (e < 32768) {                    // w2b[o][k] = bf16(w2[o][k])
    int e2 = e - 16384;
    w2b[e2] = (unsigned short)bf1u(w2[e2]);
  } else if (e < 81920) {
    int e2 = e - 32768;                      // 0..49151 sampled_coor
    int bs = e2 / 3, c = e2 - bs * 3;
    int b = bs >> 11, s = bs & 2047;
    outc[e2] = coor[(b * N_ + indx[s]) * 3 + c];
  } else {
    int p = e - 81920;                       // 0..65535 SoA pack
    const int b = p >> 13, i = p & 8191;
    const float* src = coor + (size_t)p * 3;
    float* dst = soa + b * 24576;
    dst[i]         = src[0];
    dst[8192 + i]  = src[1];
    dst[16384 + i] = src[2];
  }
}

// ---------------- KNN: threshold-select, one query per 256-thread block -------
// Output = SET of 32 smallest keys (dist_bits<<32 | idx); order arbitrary
// (downstream max/mean/var are permutation-invariant over K).
// dist[macro 0..3] in registers, macro 4..7 in LDS; NO recompute.
__global__ __launch_bounds__(256, 8) void kknn(const float* __restrict__ soa,
                                               const int* __restrict__ indx,
                                               int* __restrict__ knn) {
  __shared__ __align__(16) float4 sdist4[4 * 256];  // 16KB: dist[it-4][tid] x4
  __shared__ float sTw[8];                    // per-half-wave 4th-smallest min
  __shared__ unsigned long long cands[192];
  __shared__ int ccnt;

  const int gid = blockIdx.x;
  const int b = gid >> 11, s = gid & 2047;
  const int tid = threadIdx.x;
  const int w = tid >> 6, lane = tid & 63;
  const int hl = lane & 31;                   // half-wave lane
  const float* Xb = soa + b * 24576;
  const float* Yb = Xb + 8192;
  const float* Zb = Xb + 16384;
  const int qi = indx[s];
  const float qx = Xb[qi], qy = Yb[qi], qz = Zb[qi];
  const f32x2 nqx = {-qx, -qx}, nqy = {-qy, -qy}, nqz = {-qz, -qz};

  // pass 1: 8 macro-iters x 4 adjacent points per lane (packed fp32 math).
  // Per component: d = ((dx*dx + dy*dy) + dz*dz), dx = cx + (-qx) -- bit-exact
  // vs scalar __fsub_rn/__fmul_rn/__fadd_rn.
  f32x2 rd[8];                                // macro 0..3 -> 16 dists in regs
  float dmA = 3.4e38f, dmB = 3.4e38f;
#pragma unroll
  for (int it = 0; it < 8; ++it) {
    const int ofs = (it << 10) + (tid << 2);
    union { float4 f4; f32x2 h[2]; } X, Y, Z;
    X.f4 = *(const float4*)(Xb + ofs);
    Y.f4 = *(const float4*)(Yb + ofs);
    Z.f4 = *(const float4*)(Zb + ofs);
    const f32x2 dxl = pk_add(X.h[0], nqx), dyl = pk_add(Y.h[0], nqy),
                dzl = pk_add(Z.h[0], nqz);
    const f32x2 dxh = pk_add(X.h[1], nqx), dyh = pk_add(Y.h[1], nqy),
                dzh = pk_add(Z.h[1], nqz);
    const f32x2 sl =
        pk_add(pk_add(pk_mul(dxl, dxl), pk_mul(dyl, dyl)), pk_mul(dzl, dzl));
    const f32x2 sh =
        pk_add(pk_add(pk_mul(dxh, dxh), pk_mul(dyh, dyh)), pk_mul(dzh, dzh));
    dmA = fminf(fminf(sl.x, sl.y), dmA);      // v_min3_f32
    dmB = fminf(fminf(sh.x, sh.y), dmB);
    if (it < 4) {
      rd[it * 2] = sl;
      rd[it * 2 + 1] = sh;
    } else {
      union { float4 f4; f32x2 h[2]; } st;
      st.h[0] = sl;
      st.h[1] = sh;
      sdist4[((it - 4) << 8) + tid] = st.f4;   // one ds_write_b128
    }
  }
  float dmin = fminf(dmA, dmB);
  if (tid == 0) ccnt = 0;
  if (tid < 192) cands[tid] = ~0ULL;          // sentinel (> any real key)

  // pass 2: per-HALF-WAVE ascending bitonic sort (32 elements, 15 stages;
  // direction from hl=lane&31 so both halves sort ascending). Lane hl==3
  // holds the half-wave's 4th-smallest thread-min. T = max over the 8
  // half-waves. Each half-wave has >=4 thread-mins <= T -> >=4 distinct
  // elements <= T -> >=32 total -> T >= d32.
  float v = dmin;
#pragma unroll
  for (int k = 2; k <= 32; k <<= 1) {
#pragma unroll
    for (int j = k >> 1; j >= 1; j >>= 1) {
      const float o = __shfl_xor(v, j, 64);
      const bool dirAsc = ((hl & k) == 0);
      const bool lower = ((hl & j) == 0);
      const float lo = fminf(v, o), hi = fmaxf(v, o);
      v = (dirAsc == lower) ? lo : hi;
    }
  }
  if (hl == 3) sTw[(w << 1) + (lane >> 5)] = v;
  __syncthreads();
  const float T =
      fmaxf(fmaxf(fmaxf(sTw[0], sTw[1]), fmaxf(sTw[2], sTw[3])),
            fmaxf(fmaxf(sTw[4], sTw[5]), fmaxf(sTw[6], sTw[7])));

  // pass 3: compact candidates (dist <= T) from regs + LDS; E~55-70, cap 192.
  // Sparse predicate -> per-lane atomicAdd is cheaper than wave aggregation
  // (R19 post-mortem).
#pragma unroll
  for (int t = 0; t < 8; ++t) {
    const int p0 = ((t >> 1) << 10) + (tid << 2) + ((t & 1) << 1);
    const float d0 = rd[t].x, d1 = rd[t].y;
    if (d0 <= T) {
      const int pos = atomicAdd(&ccnt, 1);
      if (pos < 192)
        cands[pos] = ((unsigned long long)__float_as_uint(d0) << 32) |
                     (unsigned int)p0;
    }
    if (d1 <= T) {
      const int pos = atomicAdd(&ccnt, 1);
      if (pos < 192)
        cands[pos] = ((unsigned long long)__float_as_uint(d1) << 32) |
                     (unsigned int)(p0 + 1);
    }
  }
#pragma unroll
  for (int it = 4; it < 8; ++it) {
    const float4 d4 = sdist4[((it - 4) << 8) + tid];   // one ds_read_b128
    const int p0 = (it << 10) + (tid << 2);
    const float dd[4] = {d4.x, d4.y, d4.z, d4.w};
#pragma unroll
    for (int j = 0; j < 4; ++j) {
      if (dd[j] <= T) {
        const int pos = atomicAdd(&ccnt, 1);
        if (pos < 192)
          cands[pos] = ((unsigned long long)__float_as_uint(dd[j]) << 32) |
                       (unsigned int)(p0 + j);
      }
    }
  }
  __syncthreads();

  // pass 4: exact top-32 of E candidates by rank-count. Keys distinct (idx in
  // low bits) -> ranks 0..E-1 a permutation; rank<32 writes. Scan padded to
  // Ep=(E+3)&~3 with unroll-4: slots [E,192) hold ~0ULL sentinels which never
  // compare < key (real keys < ~0ULL), so rank is exact while the broadcast
  // ds_reads batch 4 per waitcnt instead of dependent singles.
  const int E = min(ccnt, 192);               // E >= 32 guaranteed
  if (tid < E) {
    const unsigned long long key = cands[tid];
    int rank = 0;
    const int Ep = (E + 3) & ~3;
#pragma unroll 4
    for (int j = 0; j < Ep; ++j) rank += (cands[j] < key) ? 1 : 0;
    if (rank < 32) knn[gid * 32 + rank] = (int)(unsigned int)key;
  }
}

// ---------------- phase kernels: MFMA fused GEMMs ----------------------------
// Wave w owns cols 32w..32w+31. Per lane: m = lane&31 (A row / D col), q2 = lane>>5.
// A layout: A[m=lane&31][k=q2*8+j]; B layout: B^T[n=lane&31][k=q2*8+j];
// C/D layout: col=lane&31, row=(reg&3)+8*(reg>>2)+4*q2  [m74/m101-verified].
// Layer-1 is K=128: A = [sx bf16 (k<64) | d bf16 (k>=64)], B = full w1.
// XCD map: batch = blockIdx&7 (one 2MB x-slice per XCD L2).
// Pipeline: central row AND gather rows for g+1 prefetched into registers;
// raw s_barrier with lgkmcnt-only drain keeps those loads in flight.
// launch_bounds: PHASE1 (256,3) -- no bf2/acc2, ~130 regs < 170, spill-free;
// PHASE2 (256,2) -- ~178 regs needs the 256 budget (R17/R18 lesson).
template <int PHASE>
__global__ __launch_bounds__(256, PHASE == 1 ? 3 : 2) void kphase(
    const float* __restrict__ x, const int* __restrict__ indx,
    const int* __restrict__ knn, const float* __restrict__ b1,
    const unsigned short* __restrict__ w1b, const unsigned short* __restrict__ w2b,
    const float* __restrict__ b2, const float* __restrict__ st1,
    float* __restrict__ part, float* __restrict__ mout) {
  __shared__ __align__(16) unsigned short sxb[2][80];          // bf16 sx x2
  __shared__ __align__(16) unsigned short dls[2][32 * 68 + 8]; // d rows x2
  __shared__ __align__(16) unsigned short h1[PHASE == 2 ? 2 * 32 * 136 : 8];

  const int tid = threadIdx.x;
  const int w = tid >> 6;
  const int lane = tid & 63;
  const int m = lane & 31, q2 = lane >> 5;
  const int col = (w << 5) + m;              // output channel of this lane
  const int r8 = tid >> 3, c8 = (tid & 7) * 8;  // staging map: row, col-base

  const int bb = blockIdx.x & 7;             // batch == target XCD
  const int jj = blockIdx.x >> 3;            // 0..127 chunk within batch
  const float* xb = x + (size_t)bb * (N_ * 64);
  const int gidbase = (bb << 11) + jj * GPB_;
  const int sbase = jj * GPB_;

  // group-invariant operands in registers
  bf8 bf1[8];
#pragma unroll
  for (int t = 0; t < 8; ++t)
    bf1[t] = *(const bf8*)&w1b[col * 128 + t * 16 + q2 * 8];
  bf8 bf2[8];
  float s1 = 0.f, t1 = 0.f, b2v = 0.f;
  if constexpr (PHASE == 2) {
#pragma unroll
    for (int t = 0; t < 8; ++t)
      bf2[t] = *(const bf8*)&w2b[col * 128 + t * 16 + q2 * 8];
    s1 = st1[col];
    t1 = st1[128 + col];
    b2v = b2[col];
  }
  (void)w2b; (void)b2; (void)st1; (void)mout;
  const float b1c = b1[col];

  float sum = 0.f, ssq = 0.f;

  // pipeline prologue: central + gather rows for g=0 into regs; indices for g=1
  float4 ca_c, cc_c, ga_c, gc_c;
  {
    const int idx0 = indx[sbase];
    const int nbr0 = knn[(size_t)gidbase * 32 + r8];
    const float* c0 = xb + (size_t)idx0 * 64;
    ca_c = *(const float4*)(c0 + c8);
    cc_c = *(const float4*)(c0 + c8 + 4);
    const float* g0 = xb + (size_t)nbr0 * 64;
    ga_c = *(const float4*)(g0 + c8);
    gc_c = *(const float4*)(g0 + c8 + 4);
  }
  int idx_nxt = (GPB_ > 1) ? indx[sbase + 1] : 0;
  int nbr_nxt = (GPB_ > 1) ? knn[(size_t)(gidbase + 1) * 32 + r8] : 0;

#pragma unroll 1
  for (int g = 0; g < GPB_; ++g) {
    const int gid = gidbase + g;
    const int p = g & 1;

    // issue prefetch for g+1 rows FIRST (stays in flight across the barrier)
    float4 ca_n = ca_c, cc_n = cc_c, ga_n = ga_c, gc_n = gc_c;
    if (g + 1 < GPB_) {
      const float* cn = xb + (size_t)idx_nxt * 64;
      ca_n = *(const float4*)(cn + c8);
      cc_n = *(const float4*)(cn + c8 + 4);
      const float* gn = xb + (size_t)nbr_nxt * 64;
      ga_n = *(const float4*)(gn + c8);
      gc_n = *(const float4*)(gn + c8 + 4);
    }
    // indices for g+2 (consumed next iteration)
    if (g + 2 < GPB_) {
      nbr_nxt = knn[(size_t)(gid + 2) * 32 + r8];
      idx_nxt = indx[sbase + g + 2];
    }

    // stage d = x[nbr] - sx as bf16 into dls[p] (regs only; loaded last iter)
    {
      uint2 lo, hi;
      lo.x = bfpair(ga_c.x - ca_c.x, ga_c.y - ca_c.y);
      lo.y = bfpair(ga_c.z - ca_c.z, ga_c.w - ca_c.w);
      hi.x = bfpair(gc_c.x - cc_c.x, gc_c.y - cc_c.y);
      hi.y = bfpair(gc_c.z - cc_c.z, gc_c.w - cc_c.w);
      *(uint2*)&dls[p][r8 * 68 + c8] = lo;     // byte addr 136*r8+16k: 8B-aligned
      *(uint2*)&dls[p][r8 * 68 + c8 + 4] = hi;
    }
    if (tid < 8) {                             // tid<8: c8==tid*8 -> holds the
      uint2 lo, hi;                            // full central row in ca/cc
      lo.x = bfpair(ca_c.x, ca_c.y);
      lo.y = bfpair(ca_c.z, ca_c.w);
      hi.x = bfpair(cc_c.x, cc_c.y);
      hi.y = bfpair(cc_c.z, cc_c.w);
      *(uint2*)&sxb[p][tid * 8] = lo;
      *(uint2*)&sxb[p][tid * 8 + 4] = hi;
    }
    // LDS-visibility-only barrier: vmcnt NOT drained -> prefetch keeps flying
    asm volatile("s_waitcnt lgkmcnt(0)" ::: "memory");
    __builtin_amdgcn_s_barrier();

    // A-frags: t<4 from sxb[p] (k<64), t>=4 from dls[p] (k>=64)
    bf8 af[8];
#pragma unroll
    for (int t = 0; t < 4; ++t) {
      union { bf8 v; uint2 u[2]; } fa;
      fa.u[0] = *(const uint2*)&sxb[p][t * 16 + q2 * 8];
      fa.u[1] = *(const uint2*)&sxb[p][t * 16 + q2 * 8 + 4];
      af[t] = fa.v;
    }
#pragma unroll
    for (int t = 0; t < 4; ++t) {
      union { bf8 v; uint2 u[2]; } fa;
      fa.u[0] = *(const uint2*)&dls[p][m * 68 + t * 16 + q2 * 8];
      fa.u[1] = *(const uint2*)&dls[p][m * 68 + t * 16 + q2 * 8 + 4];
      af[4 + t] = fa.v;
    }

    f32x16 acc;
#pragma unroll
    for (int r = 0; r < 16; ++r) acc[r] = b1c;
#pragma unroll
    for (int t = 0; t < 8; ++t)
      acc = __builtin_amdgcn_mfma_f32_32x32x16_bf16(af[t], bf1[t], acc, 0, 0, 0);

    if constexpr (PHASE == 1) {
#pragma unroll
      for (int r = 0; r < 16; ++r) {
        const float v = acc[r];
        sum += v;
        ssq = fmaf(v, v, ssq);
      }
    } else {
      // bn1 + relu -> h1[p] bf16 in LDS (C-layout scatter, row stride 136)
      const int hp = p * (32 * 136);
#pragma unroll
      for (int r = 0; r < 16; ++r) {
        const float hv = fmaxf(0.f, fmaf(acc[r], s1, t1));
        const int row = (r & 3) + ((r >> 2) << 3) + (q2 << 2);
        h1[hp + row * 136 + col] = (unsigned short)bf1u(hv);
      }
      asm volatile("s_waitcnt lgkmcnt(0)" ::: "memory");
      __builtin_amdgcn_s_barrier();            // h1[p] ready (lgkm only)

      f32x16 acc2;
#pragma unroll
      for (int r = 0; r < 16; ++r) acc2[r] = b2v;
#pragma unroll
      for (int t = 0; t < 8; ++t) {
        const bf8 a2 = *(const bf8*)&h1[hp + m * 136 + t * 16 + q2 * 8];
        acc2 = __builtin_amdgcn_mfma_f32_32x32x16_bf16(a2, bf2[t], acc2, 0, 0, 0);
      }

      float mx = -1e30f;
#pragma unroll
      for (int r = 0; r < 16; ++r) {
        const float v = acc2[r];
        sum += v;
        ssq = fmaf(v, v, ssq);
        mx = fmaxf(mx, v);
      }
      mx = fmaxf(mx, __shfl_xor(mx, 32, 64));
      if (lane < 32) mout[(size_t)gid * 128 + col] = mx;
    }

    // rotate prefetched rows
    ca_c = ca_n;
    cc_c = cc_n;
    ga_c = ga_n;
    gc_c = gc_n;
  }

  // channel partials: each channel owned by exactly one wave
  sum += __shfl_xor(sum, 32, 64);
  ssq += __shfl_xor(ssq, 32, 64);
  if (lane < 32) {
    part[blockIdx.x * 256 + col] = sum;
    part[blockIdx.x * 256 + 128 + col] = ssq;
  }
}

// ---------------- stats reduce stage 1: 64 blocks, f64 partial sums ----------
__global__ __launch_bounds__(256) void kred1(const float* __restrict__ part,
                                             double* __restrict__ dbuf) {
  const int blk = blockIdx.x;                // 0..63: rows 16*blk..16*blk+15
  const int c = threadIdx.x;                 // 0..255 (128 sums | 128 ssqs)
  const float* p = part + (size_t)blk * 16 * 256 + c;
  double acc = 0.0;
#pragma unroll
  for (int r = 0; r < 16; ++r) acc += (double)p[r * 256];
  dbuf[blk * 256 + c] = acc;
}

// ---------------- stats reduce stage 2: finalize scale/shift -----------------
__global__ __launch_bounds__(256) void kred2(const double* __restrict__ dbuf,
                                             const float* __restrict__ gam,
                                             const float* __restrict__ bet,
                                             float* __restrict__ st) {
  __shared__ double sS[256];
  const int c = threadIdx.x;
  double acc = 0.0;
#pragma unroll 8
  for (int i = 0; i < 64; ++i) acc += dbuf[i * 256 + c];
  sS[c] = acc;
  __syncthreads();
  if (c < 128) {
    const double Sv = sS[c], SSv = sS[128 + c];
    const double cnt = 524288.0;             // B*S*K
    const double mean = Sv / cnt;
    const double var = SSv / cnt - mean * mean;
    const double scale = (double)gam[c] / sqrt(var + 1e-5);
    st[c] = (float)scale;
    st[128 + c] = (float)((double)bet[c] - mean * scale);
  }
}

// ---------------- final: out = relu(scale2 * max_k(y2) + shift2) -------------
__global__ __launch_bounds__(256) void kout(const float* __restrict__ m,
                                            const float* __restrict__ st2,
                                            float* __restrict__ out) {
  const int e4 = blockIdx.x * 256 + threadIdx.x;  // 524288 float4s
  const int o0 = (e4 & 31) * 4;
  const float4 v = ((const float4*)m)[e4];
  const float4 sc = *(const float4*)&st2[o0];
  const float4 sh = *(const float4*)&st2[128 + o0];
  float4 r;
  r.x = fmaxf(0.f, fmaf(v.x, sc.x, sh.x));
  r.y = fmaxf(0.f, fmaf(v.y, sc.y, sh.y));
  r.z = fmaxf(0.f, fmaf(v.z, sc.z, sh.z));
  r.w = fmaxf(0.f, fmaf(v.w, sc.w, sh.w));
  ((float4*)out)[e4] = r;
}

extern "C" void kernel_launch(void* const* d_in, const int* in_sizes, int n_in,
                              void* d_out, int out_size, void* d_ws, size_t ws_size,
                              hipStream_t stream) {
  (void)in_sizes; (void)n_in; (void)out_size; (void)ws_size;
  const float* x    = (const float*)d_in[0];
  const float* coor = (const float*)d_in[1];
  const int*   indx = (const int*)d_in[2];
  const float* w1   = (const float*)d_in[3];
  const float* b1   = (const float*)d_in[4];
  const float* g1   = (const float*)d_in[5];
  const float* be1  = (const float*)d_in[6];
  const float* w2   = (const float*)d_in[7];
  const float* b2   = (const float*)d_in[8];
  const float* g2   = (const float*)d_in[9];
  const float* be2  = (const float*)d_in[10];
  float* out = (float*)d_out;

  char* ws = (char*)d_ws;
  int*            knn   = (int*)(ws + 0);
  float*          mbuf  = (float*)(ws + 2097152);
  float*          part1 = (float*)(ws + 10485760);
  float*          soa   = (float*)(ws + 10485760); // aliases part1 (disjoint lifetime)
  float*          part2 = (float*)(ws + 12582912);
  unsigned short* w1b   = (unsigned short*)(ws + 14680064);
  unsigned short* w2b   = (unsigned short*)(ws + 14712832);
  float*          st1   = (float*)(ws + 14745600);
  float*          st2   = (float*)(ws + 14746624);
  double*         dbuf  = (double*)(ws + 14747648);

  float* outc = out + 2097152;   // sampled_coor region of d_out

  kprep<<<576, 256, 0, stream>>>(w1, w2, coor, indx, w1b, w2b, outc, soa);
  kknn<<<16384, 256, 0, stream>>>(soa, indx, knn);
  kphase<1><<<1024, 256, 0, stream>>>(x, indx, knn, b1, w1b, w2b, b2, nullptr,
                                      part1, nullptr);
  kred1<<<64, 256, 0, stream>>>(part1, dbuf);
  kred2<<<1, 256, 0, stream>>>(dbuf, g1, be1, st1);
  kphase<2><<<1024, 256, 0, stream>>>(x, indx, knn, b1, w1b, w2b, b2, st1,
                                      part2, mbuf);
  kred1<<<64, 256, 0, stream>>>(part2, dbuf);
  kred2<<<1, 256, 0, stream>>>(dbuf, g2, be2, st2);
  kout<<<2048, 256, 0, stream>>>(mbuf, st2, out);
}

// Round 12
// 243.353 us; speedup vs baseline: 1.1394x; 1.0160x over previous
//
#include <hip/hip_runtime.h>
#include <stdint.h>

// sample_and_group: B=8 N=8192 C=64 S=2048 K=32 OUT=128
// out = (out[8,2048,128], sampled_coor[8,2048,3]) concatenated in d_out (float32).
//
// R25: kphase PAIR processing — two groups per barrier segment.
// Mechanism (R23 counters: MfmaUtil 15.8, VALUBusy 24, ~60% idle): per-group
// barriers lockstep all 4 waves on the slowest straggler with only 2 blocks/CU
// of cover. Pairing halves barrier frequency (phase1 1->0.5/group, phase2
// 2->1/group), doubles MFMA per segment (16), and gives pair-issued prefetch
// (g+2,g+3) a full pair-period to land.
// Correctness: dls/sxb rotate over 4 buffers -> consecutive pairs use disjoint
// buffers; buffer (g&3) is re-staged at pair p only after barrier B1(p) which
// orders it after pair p-2's reads (its last readers). h1[0/1] are pair
// members guarded by the pack-barrier exactly as before. All staging math,
// MFMA layouts, stats, and outputs byte-identical to R24 -> bit-exact.
// Both phases (256,2): regs ~169/~223 est., no spill risk (R17 lesson).
// kknn frozen (structural floor: VALU 66-70% busy, micro-opts in-noise).
//
// Workspace layout (bytes):
//   [0,2MB)        knn indices  int32[16384*32]
//   [2MB,10MB)     m = max_k y2 f32[16384*128]
//   [10MB,11MB)    soa coords  f32[8][3][8192] (ALIASES part1; kknn-only lifetime)
//   [10MB,12MB)    partials1    f32[1024*256]
//   [12MB,14MB)    partials2    f32[1024*256]
//   [14MB,+32KB)   w1b  bf16 [o][k=0..127]
//   [..,+32KB)     w2b  bf16 [o][k=0..127]
//   [..,+1KB)      stats1 (scale[128], shift[128])
//   [..,+1KB)      stats2
//   [..,+128KB)    dbuf f64[64*256] (reduce stage-1 output)

#define N_    8192
#define GPB_  16      // groups per block in phase kernels (must be even)

typedef __attribute__((ext_vector_type(8))) short bf8;
typedef __attribute__((ext_vector_type(16))) float f32x16;
typedef __attribute__((ext_vector_type(2))) float f32x2;

__device__ __forceinline__ unsigned int bf1u(float f) {   // RNE fp32->bf16 bits
  unsigned int u = __float_as_uint(f);
  return (u + 0x7fffu + ((u >> 16) & 1u)) >> 16;
}
__device__ __forceinline__ unsigned int bfpair(float lo, float hi) {
  return bf1u(lo) | (bf1u(hi) << 16);
}

// packed fp32 VOP3P helpers (CDNA: 2x fp32 per instruction, IEEE RN per lane)
__device__ __forceinline__ f32x2 pk_add(f32x2 a, f32x2 b) {
  f32x2 d;
  asm("v_pk_add_f32 %0, %1, %2" : "=v"(d) : "v"(a), "v"(b));
  return d;
}
__device__ __forceinline__ f32x2 pk_mul(f32x2 a, f32x2 b) {
  f32x2 d;
  asm("v_pk_mul_f32 %0, %1, %2" : "=v"(d) : "v"(a), "v"(b));
  return d;
}

// ---------------- prep: weight layouts + SoA coord pack + sampled_coor -------
__global__ __launch_bounds__(256) void kprep(const float* __restrict__ w1,
                                             const float* __restrict__ w2,
                                             const float* __restrict__ coor,
                                             const int* __restrict__ indx,
                                             unsigned short* __restrict__ w1b,
                                             unsigned short* __restrict__ w2b,
                                             float* __restrict__ outc,
                                             float* __restrict__ soa) {
  int e = blockIdx.x * 256 + threadIdx.x;   // grid is exactly 576*256 = 147456
  if (e < 16384) {                           // w1b[o][k] = bf16(w1[o][k])
    w1b[e] = (unsigned short)bf1u(w1[e]);
  } else if (e < 32768) {                    // w2b[o][k] = bf16(w2[o][k])
    int e2 = e - 16384;
    w2b[e2] = (unsigned short)bf1u(w2[e2]);
  } else if (e < 81920) {
    int e2 = e - 32768;                      // 0..49151 sampled_coor
    int bs = e2 / 3, c = e2 - bs * 3;
    int b = bs >> 11, s = bs & 2047;
    outc[e2] = coor[(b * N_ + indx[s]) * 3 + c];
  } else {
    int p = e - 81920;                       // 0..65535 SoA pack
    const int b = p >> 13, i = p & 8191;
    const float* src = coor + (size_t)p * 3;
    float* dst = soa + b * 24576;
    dst[i]         = src[0];
    dst[8192 + i]  = src[1];
    dst[16384 + i] = src[2];
  }
}

// ---------------- KNN: threshold-select, one query per 256-thread block -------
// Output = SET of 32 smallest keys (dist_bits<<32 | idx); order arbitrary
// (downstream max/mean/var are permutation-invariant over K).
// dist[macro 0..3] in registers, macro 4..7 in LDS; NO recompute.
__global__ __launch_bounds__(256, 8) void kknn(const float* __restrict__ soa,
                                               const int* __restrict__ indx,
                                               int* __restrict__ knn) {
  __shared__ __align__(16) float4 sdist4[4 * 256];  // 16KB: dist[it-4][tid] x4
  __shared__ float sTw[8];                    // per-half-wave 4th-smallest min
  __shared__ unsigned long long cands[192];
  __shared__ int ccnt;

  const int gid = blockIdx.x;
  const int b = gid >> 11, s = gid & 2047;
  const int tid = threadIdx.x;
  const int w = tid >> 6, lane = tid & 63;
  const int hl = lane & 31;                   // half-wave lane
  const float* Xb = soa + b * 24576;
  const float* Yb = Xb + 8192;
  const float* Zb = Xb + 16384;
  const int qi = indx[s];
  const float qx = Xb[qi], qy = Yb[qi], qz = Zb[qi];
  const f32x2 nqx = {-qx, -qx}, nqy = {-qy, -qy}, nqz = {-qz, -qz};

  // pass 1: 8 macro-iters x 4 adjacent points per lane (packed fp32 math).
  // Per component: d = ((dx*dx + dy*dy) + dz*dz), dx = cx + (-qx) -- bit-exact
  // vs scalar __fsub_rn/__fmul_rn/__fadd_rn.
  f32x2 rd[8];                                // macro 0..3 -> 16 dists in regs
  float dmA = 3.4e38f, dmB = 3.4e38f;
#pragma unroll
  for (int it = 0; it < 8; ++it) {
    const int ofs = (it << 10) + (tid << 2);
    union { float4 f4; f32x2 h[2]; } X, Y, Z;
    X.f4 = *(const float4*)(Xb + ofs);
    Y.f4 = *(const float4*)(Yb + ofs);
    Z.f4 = *(const float4*)(Zb + ofs);
    const f32x2 dxl = pk_add(X.h[0], nqx), dyl = pk_add(Y.h[0], nqy),
                dzl = pk_add(Z.h[0], nqz);
    const f32x2 dxh = pk_add(X.h[1], nqx), dyh = pk_add(Y.h[1], nqy),
                dzh = pk_add(Z.h[1], nqz);
    const f32x2 sl =
        pk_add(pk_add(pk_mul(dxl, dxl), pk_mul(dyl, dyl)), pk_mul(dzl, dzl));
    const f32x2 sh =
        pk_add(pk_add(pk_mul(dxh, dxh), pk_mul(dyh, dyh)), pk_mul(dzh, dzh));
    dmA = fminf(fminf(sl.x, sl.y), dmA);      // v_min3_f32
    dmB = fminf(fminf(sh.x, sh.y), dmB);
    if (it < 4) {
      rd[it * 2] = sl;
      rd[it * 2 + 1] = sh;
    } else {
      union { float4 f4; f32x2 h[2]; } st;
      st.h[0] = sl;
      st.h[1] = sh;
      sdist4[((it - 4) << 8) + tid] = st.f4;   // one ds_write_b128
    }
  }
  float dmin = fminf(dmA, dmB);
  if (tid == 0) ccnt = 0;
  if (tid < 192) cands[tid] = ~0ULL;          // sentinel (> any real key)

  // pass 2: per-HALF-WAVE ascending bitonic sort (32 elements, 15 stages;
  // direction from hl=lane&31 so both halves sort ascending). Lane hl==3
  // holds the half-wave's 4th-smallest thread-min. T = max over the 8
  // half-waves. Each half-wave has >=4 thread-mins <= T -> >=4 distinct
  // elements <= T -> >=32 total -> T >= d32.
  float v = dmin;
#pragma unroll
  for (int k = 2; k <= 32; k <<= 1) {
#pragma unroll
    for (int j = k >> 1; j >= 1; j >>= 1) {
      const float o = __shfl_xor(v, j, 64);
      const bool dirAsc = ((hl & k) == 0);
      const bool lower = ((hl & j) == 0);
      const float lo = fminf(v, o), hi = fmaxf(v, o);
      v = (dirAsc == lower) ? lo : hi;
    }
  }
  if (hl == 3) sTw[(w << 1) + (lane >> 5)] = v;
  __syncthreads();
  const float T =
      fmaxf(fmaxf(fmaxf(sTw[0], sTw[1]), fmaxf(sTw[2], sTw[3])),
            fmaxf(fmaxf(sTw[4], sTw[5]), fmaxf(sTw[6], sTw[7])));

  // pass 3: compact candidates (dist <= T) from regs + LDS; E~55-70, cap 192.
  // Sparse predicate -> per-lane atomicAdd is cheaper than wave aggregation
  // (R19 post-mortem).
#pragma unroll
  for (int t = 0; t < 8; ++t) {
    const int p0 = ((t >> 1) << 10) + (tid << 2) + ((t & 1) << 1);
    const float d0 = rd[t].x, d1 = rd[t].y;
    if (d0 <= T) {
      const int pos = atomicAdd(&ccnt, 1);
      if (pos < 192)
        cands[pos] = ((unsigned long long)__float_as_uint(d0) << 32) |
                     (unsigned int)p0;
    }
    if (d1 <= T) {
      const int pos = atomicAdd(&ccnt, 1);
      if (pos < 192)
        cands[pos] = ((unsigned long long)__float_as_uint(d1) << 32) |
                     (unsigned int)(p0 + 1);
    }
  }
#pragma unroll
  for (int it = 4; it < 8; ++it) {
    const float4 d4 = sdist4[((it - 4) << 8) + tid];   // one ds_read_b128
    const int p0 = (it << 10) + (tid << 2);
    const float dd[4] = {d4.x, d4.y, d4.z, d4.w};
#pragma unroll
    for (int j = 0; j < 4; ++j) {
      if (dd[j] <= T) {
        const int pos = atomicAdd(&ccnt, 1);
        if (pos < 192)
          cands[pos] = ((unsigned long long)__float_as_uint(dd[j]) << 32) |
                       (unsigned int)(p0 + j);
      }
    }
  }
  __syncthreads();

  // pass 4: exact top-32 of E candidates by rank-count. Keys distinct (idx in
  // low bits) -> ranks 0..E-1 a permutation; rank<32 writes. Scan padded to
  // Ep=(E+3)&~3 with unroll-4: slots [E,192) hold ~0ULL sentinels which never
  // compare < key (real keys < ~0ULL), so rank is exact while the broadcast
  // ds_reads batch 4 per waitcnt instead of dependent singles.
  const int E = min(ccnt, 192);               // E >= 32 guaranteed
  if (tid < E) {
    const unsigned long long key = cands[tid];
    int rank = 0;
    const int Ep = (E + 3) & ~3;
#pragma unroll 4
    for (int j = 0; j < Ep; ++j) rank += (cands[j] < key) ? 1 : 0;
    if (rank < 32) knn[gid * 32 + rank] = (int)(unsigned int)key;
  }
}

// ---------------- phase kernels: MFMA fused GEMMs ----------------------------
// Wave w owns cols 32w..32w+31. Per lane: m = lane&31 (A row / D col), q2 = lane>>5.
// A layout: A[m=lane&31][k=q2*8+j]; B layout: B^T[n=lane&31][k=q2*8+j];
// C/D layout: col=lane&31, row=(reg&3)+8*(reg>>2)+4*q2  [m74/m101-verified].
// Layer-1 is K=128: A = [sx bf16 (k<64) | d bf16 (k>=64)], B = full w1.
// XCD map: batch = blockIdx&7 (one 2MB x-slice per XCD L2).
// PAIR pipeline (R25): two groups per barrier segment, 4-deep dls/sxb
// rotation, pair-issued register prefetch; lgkm-only barriers (vmcnt never
// drained -> prefetch loads fly across barriers).
template <int PHASE>
__global__ __launch_bounds__(256, 2) void kphase(
    const float* __restrict__ x, const int* __restrict__ indx,
    const int* __restrict__ knn, const float* __restrict__ b1,
    const unsigned short* __restrict__ w1b, const unsigned short* __restrict__ w2b,
    const float* __restrict__ b2, const float* __restrict__ st1,
    float* __restrict__ part, float* __restrict__ mout) {
  __shared__ __align__(16) unsigned short sxb[4][80];          // bf16 sx x4
  __shared__ __align__(16) unsigned short dls[4][32 * 68 + 8]; // d rows x4
  __shared__ __align__(16) unsigned short h1[PHASE == 2 ? 2 * 32 * 136 : 8];

  const int tid = threadIdx.x;
  const int w = tid >> 6;
  const int lane = tid & 63;
  const int m = lane & 31, q2 = lane >> 5;
  const int col = (w << 5) + m;              // output channel of this lane
  const int r8 = tid >> 3, c8 = (tid & 7) * 8;  // staging map: row, col-base

  const int bb = blockIdx.x & 7;             // batch == target XCD
  const int jj = blockIdx.x >> 3;            // 0..127 chunk within batch
  const float* xb = x + (size_t)bb * (N_ * 64);
  const int gidbase = (bb << 11) + jj * GPB_;
  const int sbase = jj * GPB_;

  // group-invariant operands in registers
  bf8 bf1[8];
#pragma unroll
  for (int t = 0; t < 8; ++t)
    bf1[t] = *(const bf8*)&w1b[col * 128 + t * 16 + q2 * 8];
  bf8 bf2[8];
  float s1 = 0.f, t1 = 0.f, b2v = 0.f;
  if constexpr (PHASE == 2) {
#pragma unroll
    for (int t = 0; t < 8; ++t)
      bf2[t] = *(const bf8*)&w2b[col * 128 + t * 16 + q2 * 8];
    s1 = st1[col];
    t1 = st1[128 + col];
    b2v = b2[col];
  }
  (void)w2b; (void)b2; (void)st1; (void)mout;
  const float b1c = b1[col];

  float sum = 0.f, ssq = 0.f;

  // prologue: load pair (g=0, g=1) rows into regs; indices for pair (2,3)
  float4 caA, ccA, gaA, gcA, caB, ccB, gaB, gcB;
  {
    const int idxA = indx[sbase];
    const int idxB = indx[sbase + 1];
    const int nbrA = knn[(size_t)gidbase * 32 + r8];
    const int nbrB = knn[(size_t)(gidbase + 1) * 32 + r8];
    const float* cA = xb + (size_t)idxA * 64;
    caA = *(const float4*)(cA + c8);
    ccA = *(const float4*)(cA + c8 + 4);
    const float* gA = xb + (size_t)nbrA * 64;
    gaA = *(const float4*)(gA + c8);
    gcA = *(const float4*)(gA + c8 + 4);
    const float* cB = xb + (size_t)idxB * 64;
    caB = *(const float4*)(cB + c8);
    ccB = *(const float4*)(cB + c8 + 4);
    const float* gB = xb + (size_t)nbrB * 64;
    gaB = *(const float4*)(gB + c8);
    gcB = *(const float4*)(gB + c8 + 4);
  }
  int idxA2 = (GPB_ > 2) ? indx[sbase + 2] : 0;
  int idxB2 = (GPB_ > 3) ? indx[sbase + 3] : 0;
  int nbrA2 = (GPB_ > 2) ? knn[(size_t)(gidbase + 2) * 32 + r8] : 0;
  int nbrB2 = (GPB_ > 3) ? knn[(size_t)(gidbase + 3) * 32 + r8] : 0;

#pragma unroll 1
  for (int g = 0; g < GPB_; g += 2) {
    const int gid = gidbase + g;
    const int p0 = g & 3, p1 = (g + 1) & 3;

    // issue prefetch for pair (g+2, g+3) FIRST (flies across the barriers)
    float4 caA_n = caA, ccA_n = ccA, gaA_n = gaA, gcA_n = gcA;
    float4 caB_n = caB, ccB_n = ccB, gaB_n = gaB, gcB_n = gcB;
    if (g + 2 < GPB_) {
      const float* cA = xb + (size_t)idxA2 * 64;
      caA_n = *(const float4*)(cA + c8);
      ccA_n = *(const float4*)(cA + c8 + 4);
      const float* gA = xb + (size_t)nbrA2 * 64;
      gaA_n = *(const float4*)(gA + c8);
      gcA_n = *(const float4*)(gA + c8 + 4);
      const float* cB = xb + (size_t)idxB2 * 64;
      caB_n = *(const float4*)(cB + c8);
      ccB_n = *(const float4*)(cB + c8 + 4);
      const float* gB = xb + (size_t)nbrB2 * 64;
      gaB_n = *(const float4*)(gB + c8);
      gcB_n = *(const float4*)(gB + c8 + 4);
    }
    if (g + 4 < GPB_) {                      // indices for pair (g+4, g+5)
      nbrA2 = knn[(size_t)(gid + 4) * 32 + r8];
      nbrB2 = knn[(size_t)(gid + 5) * 32 + r8];
      idxA2 = indx[sbase + g + 4];
      idxB2 = indx[sbase + g + 5];
    }

    // stage BOTH groups: d = x[nbr] - sx as bf16 (regs loaded last iter)
    {
      uint2 lo, hi;
      lo.x = bfpair(gaA.x - caA.x, gaA.y - caA.y);
      lo.y = bfpair(gaA.z - caA.z, gaA.w - caA.w);
      hi.x = bfpair(gcA.x - ccA.x, gcA.y - ccA.y);
      hi.y = bfpair(gcA.z - ccA.z, gcA.w - ccA.w);
      *(uint2*)&dls[p0][r8 * 68 + c8] = lo;
      *(uint2*)&dls[p0][r8 * 68 + c8 + 4] = hi;
      lo.x = bfpair(gaB.x - caB.x, gaB.y - caB.y);
      lo.y = bfpair(gaB.z - caB.z, gaB.w - caB.w);
      hi.x = bfpair(gcB.x - ccB.x, gcB.y - ccB.y);
      hi.y = bfpair(gcB.z - ccB.z, gcB.w - ccB.w);
      *(uint2*)&dls[p1][r8 * 68 + c8] = lo;
      *(uint2*)&dls[p1][r8 * 68 + c8 + 4] = hi;
    }
    if (tid < 8) {                           // tid<8: c8==tid*8 -> full sx row
      uint2 lo, hi;
      lo.x = bfpair(caA.x, caA.y);
      lo.y = bfpair(caA.z, caA.w);
      hi.x = bfpair(ccA.x, ccA.y);
      hi.y = bfpair(ccA.z, ccA.w);
      *(uint2*)&sxb[p0][tid * 8] = lo;
      *(uint2*)&sxb[p0][tid * 8 + 4] = hi;
      lo.x = bfpair(caB.x, caB.y);
      lo.y = bfpair(caB.z, caB.w);
      hi.x = bfpair(ccB.x, ccB.y);
      hi.y = bfpair(ccB.z, ccB.w);
      *(uint2*)&sxb[p1][tid * 8] = lo;
      *(uint2*)&sxb[p1][tid * 8 + 4] = hi;
    }
    // LDS-visibility-only barrier: vmcnt NOT drained
    asm volatile("s_waitcnt lgkmcnt(0)" ::: "memory");
    __builtin_amdgcn_s_barrier();

    // ---- GEMM1 for both pair members (16 MFMA in this segment) ----
#pragma unroll
    for (int mem = 0; mem < 2; ++mem) {
      const int pb = mem == 0 ? p0 : p1;
      bf8 af[8];
#pragma unroll
      for (int t = 0; t < 4; ++t) {
        union { bf8 v; uint2 u[2]; } fa;
        fa.u[0] = *(const uint2*)&sxb[pb][t * 16 + q2 * 8];
        fa.u[1] = *(const uint2*)&sxb[pb][t * 16 + q2 * 8 + 4];
        af[t] = fa.v;
      }
#pragma unroll
      for (int t = 0; t < 4; ++t) {
        union { bf8 v; uint2 u[2]; } fa;
        fa.u[0] = *(const uint2*)&dls[pb][m * 68 + t * 16 + q2 * 8];
        fa.u[1] = *(const uint2*)&dls[pb][m * 68 + t * 16 + q2 * 8 + 4];
        af[4 + t] = fa.v;
      }
      f32x16 acc;
#pragma unroll
      for (int r = 0; r < 16; ++r) acc[r] = b1c;
#pragma unroll
      for (int t = 0; t < 8; ++t)
        acc = __builtin_amdgcn_mfma_f32_32x32x16_bf16(af[t], bf1[t], acc, 0, 0, 0);

      if constexpr (PHASE == 1) {
#pragma unroll
        for (int r = 0; r < 16; ++r) {
          const float v = acc[r];
          sum += v;
          ssq = fmaf(v, v, ssq);
        }
      } else {
        const int hp = mem * (32 * 136);     // bn1+relu -> h1[mem]
#pragma unroll
        for (int r = 0; r < 16; ++r) {
          const float hv = fmaxf(0.f, fmaf(acc[r], s1, t1));
          const int row = (r & 3) + ((r >> 2) << 3) + (q2 << 2);
          h1[hp + row * 136 + col] = (unsigned short)bf1u(hv);
        }
      }
    }

    if constexpr (PHASE == 2) {
      asm volatile("s_waitcnt lgkmcnt(0)" ::: "memory");
      __builtin_amdgcn_s_barrier();          // h1[0],h1[1] ready (lgkm only)
#pragma unroll
      for (int mem = 0; mem < 2; ++mem) {
        const int hp = mem * (32 * 136);
        f32x16 acc2;
#pragma unroll
        for (int r = 0; r < 16; ++r) acc2[r] = b2v;
#pragma unroll
        for (int t = 0; t < 8; ++t) {
          const bf8 a2 = *(const bf8*)&h1[hp + m * 136 + t * 16 + q2 * 8];
          acc2 = __builtin_amdgcn_mfma_f32_32x32x16_bf16(a2, bf2[t], acc2, 0, 0, 0);
        }
        float mx = -1e30f;
#pragma unroll
        for (int r = 0; r < 16; ++r) {
          const float v = acc2[r];
          sum += v;
          ssq = fmaf(v, v, ssq);
          mx = fmaxf(mx, v);
        }
        mx = fmaxf(mx, __shfl_xor(mx, 32, 64));
        if (lane < 32) mout[(size_t)(gid + mem) * 128 + col] = mx;
      }
    }

    // rotate prefetched pair regs
    caA = caA_n; ccA = ccA_n; gaA = gaA_n; gcA = gcA_n;
    caB = caB_n; ccB = ccB_n; gaB = gaB_n; gcB = gcB_n;
  }

  // channel partials: each channel owned by exactly one wave
  sum += __shfl_xor(sum, 32, 64);
  ssq += __shfl_xor(ssq, 32, 64);
  if (lane < 32) {
    part[blockIdx.x * 256 + col] = sum;
    part[blockIdx.x * 256 + 128 + col] = ssq;
  }
}

// ---------------- stats reduce stage 1: 64 blocks, f64 partial sums ----------
__global__ __launch_bounds__(256) void kred1(const float* __restrict__ part,
                                             double* __restrict__ dbuf) {
  const int blk = blockIdx.x;                // 0..63: rows 16*blk..16*blk+15
  const int c = threadIdx.x;                 // 0..255 (128 sums | 128 ssqs)
  const float* p = part + (size_t)blk * 16 * 256 + c;
  double acc = 0.0;
#pragma unroll
  for (int r = 0; r < 16; ++r) acc += (double)p[r * 256];
  dbuf[blk * 256 + c] = acc;
}

// ---------------- stats reduce stage 2: finalize scale/shift -----------------
__global__ __launch_bounds__(256) void kred2(const double* __restrict__ dbuf,
                                             const float* __restrict__ gam,
                                             const float* __restrict__ bet,
                                             float* __restrict__ st) {
  __shared__ double sS[256];
  const int c = threadIdx.x;
  double acc = 0.0;
#pragma unroll 8
  for (int i = 0; i < 64; ++i) acc += dbuf[i * 256 + c];
  sS[c] = acc;
  __syncthreads();
  if (c < 128) {
    const double Sv = sS[c], SSv = sS[128 + c];
    const double cnt = 524288.0;             // B*S*K
    const double mean = Sv / cnt;
    const double var = SSv / cnt - mean * mean;
    const double scale = (double)gam[c] / sqrt(var + 1e-5);
    st[c] = (float)scale;
    st[128 + c] = (float)((double)bet[c] - mean * scale);
  }
}

// ---------------- final: out = relu(scale2 * max_k(y2) + shift2) -------------
__global__ __launch_bounds__(256) void kout(const float* __restrict__ m,
                                            const float* __restrict__ st2,
                                            float* __restrict__ out) {
  const int e4 = blockIdx.x * 256 + threadIdx.x;  // 524288 float4s
  const int o0 = (e4 & 31) * 4;
  const float4 v = ((const float4*)m)[e4];
  const float4 sc = *(const float4*)&st2[o0];
  const float4 sh = *(const float4*)&st2[128 + o0];
  float4 r;
  r.x = fmaxf(0.f, fmaf(v.x, sc.x, sh.x));
  r.y = fmaxf(0.f, fmaf(v.y, sc.y, sh.y));
  r.z = fmaxf(0.f, fmaf(v.z, sc.z, sh.z));
  r.w = fmaxf(0.f, fmaf(v.w, sc.w, sh.w));
  ((float4*)out)[e4] = r;
}

extern "C" void kernel_launch(void* const* d_in, const int* in_sizes, int n_in,
                              void* d_out, int out_size, void* d_ws, size_t ws_size,
                              hipStream_t stream) {
  (void)in_sizes; (void)n_in; (void)out_size; (void)ws_size;
  const float* x    = (const float*)d_in[0];
  const float* coor = (const float*)d_in[1];
  const int*   indx = (const int*)d_in[2];
  const float* w1   = (const float*)d_in[3];
  const float* b1   = (const float*)d_in[4];
  const float* g1   = (const float*)d_in[5];
  const float* be1  = (const float*)d_in[6];
  const float* w2   = (const float*)d_in[7];
  const float* b2   = (const float*)d_in[8];
  const float* g2   = (const float*)d_in[9];
  const float* be2  = (const float*)d_in[10];
  float* out = (float*)d_out;

  char* ws = (char*)d_ws;
  int*            knn   = (int*)(ws + 0);
  float*          mbuf  = (float*)(ws + 2097152);
  float*          part1 = (float*)(ws + 10485760);
  float*          soa   = (float*)(ws + 10485760); // aliases part1 (disjoint lifetime)
  float*          part2 = (float*)(ws + 12582912);
  unsigned short* w1b   = (unsigned short*)(ws + 14680064);
  unsigned short* w2b   = (unsigned short*)(ws + 14712832);
  float*          st1   = (float*)(ws + 14745600);
  float*          st2   = (float*)(ws + 14746624);
  double*         dbuf  = (double*)(ws + 14747648);

  float* outc = out + 2097152;   // sampled_coor region of d_out

  kprep<<<576, 256, 0, stream>>>(w1, w2, coor, indx, w1b, w2b, outc, soa);
  kknn<<<16384, 256, 0, stream>>>(soa, indx, knn);
  kphase<1><<<1024, 256, 0, stream>>>(x, indx, knn, b1, w1b, w2b, b2, nullptr,
                                      part1, nullptr);
  kred1<<<64, 256, 0, stream>>>(part1, dbuf);
  kred2<<<1, 256, 0, stream>>>(dbuf, g1, be1, st1);
  kphase<2><<<1024, 256, 0, stream>>>(x, indx, knn, b1, w1b, w2b, b2, st1,
                                      part2, mbuf);
  kred1<<<64, 256, 0, stream>>>(part2, dbuf);
  kred2<<<1, 256, 0, stream>>>(dbuf, g2, be2, st2);
  kout<<<2048, 256, 0, stream>>>(mbuf, st2, out);
}

// Round 14
// 240.801 us; speedup vs baseline: 1.1515x; 1.0106x over previous
//
#include <hip/hip_runtime.h>
#include <stdint.h>

// sample_and_group: B=8 N=8192 C=64 S=2048 K=32 OUT=128
// out = (out[8,2048,128], sampled_coor[8,2048,3]) concatenated in d_out (float32).
//
// R27: exact revert to R25 (last passing state, 243.4us). R26's fused
// kred1+kred2 (last-block finalize) coincided with a container failure; its
// counter lived at ws+14878720 = 4 bytes past the previously-validated
// workspace extent (dbuf end) -> prime suspect is an OOB device write in
// kprep. Fusion upside was only ~5-10us; reverting rather than re-risking.
// If R27 passes at ~243us the R26 change is banned (like recompute).
//
// R25 structure: kphase PAIR processing (two groups per barrier segment,
// 4-deep dls/sxb rotation, pair-issued reg prefetch, lgkm-only barriers);
// kknn frozen at its VALU floor (~84us); separate kred1/kred2.
//
// Workspace layout (bytes):
//   [0,2MB)        knn indices  int32[16384*32]
//   [2MB,10MB)     m = max_k y2 f32[16384*128]
//   [10MB,11MB)    soa coords  f32[8][3][8192] (ALIASES part1; kknn-only lifetime)
//   [10MB,12MB)    partials1    f32[1024*256]
//   [12MB,14MB)    partials2    f32[1024*256]
//   [14MB,+32KB)   w1b  bf16 [o][k=0..127]
//   [..,+32KB)     w2b  bf16 [o][k=0..127]
//   [..,+1KB)      stats1 (scale[128], shift[128])
//   [..,+1KB)      stats2
//   [..,+128KB)    dbuf f64[64*256] (reduce stage-1 output)

#define N_    8192
#define GPB_  16      // groups per block in phase kernels (must be even)

typedef __attribute__((ext_vector_type(8))) short bf8;
typedef __attribute__((ext_vector_type(16))) float f32x16;
typedef __attribute__((ext_vector_type(2))) float f32x2;

__device__ __forceinline__ unsigned int bf1u(float f) {   // RNE fp32->bf16 bits
  unsigned int u = __float_as_uint(f);
  return (u + 0x7fffu + ((u >> 16) & 1u)) >> 16;
}
__device__ __forceinline__ unsigned int bfpair(float lo, float hi) {
  return bf1u(lo) | (bf1u(hi) << 16);
}

// packed fp32 VOP3P helpers (CDNA: 2x fp32 per instruction, IEEE RN per lane)
__device__ __forceinline__ f32x2 pk_add(f32x2 a, f32x2 b) {
  f32x2 d;
  asm("v_pk_add_f32 %0, %1, %2" : "=v"(d) : "v"(a), "v"(b));
  return d;
}
__device__ __forceinline__ f32x2 pk_mul(f32x2 a, f32x2 b) {
  f32x2 d;
  asm("v_pk_mul_f32 %0, %1, %2" : "=v"(d) : "v"(a), "v"(b));
  return d;
}

// ---------------- prep: weight layouts + SoA coord pack + sampled_coor -------
__global__ __launch_bounds__(256) void kprep(const float* __restrict__ w1,
                                             const float* __restrict__ w2,
                                             const float* __restrict__ coor,
                                             const int* __restrict__ indx,
                                             unsigned short* __restrict__ w1b,
                                             unsigned short* __restrict__ w2b,
                                             float* __restrict__ outc,
                                             float* __restrict__ soa) {
  int e = blockIdx.x * 256 + threadIdx.x;   // grid is exactly 576*256 = 147456
  if (e < 16384) {                           // w1b[o][k] = bf16(w1[o][k])
    w1b[e] = (unsigned short)bf1u(w1[e]);
  } else if (e < 32768) {                    // w2b[o][k] = bf16(w2[o][k])
    int e2 = e - 16384;
    w2b[e2] = (unsigned short)bf1u(w2[e2]);
  } else if (e < 81920) {
    int e2 = e - 32768;                      // 0..49151 sampled_coor
    int bs = e2 / 3, c = e2 - bs * 3;
    int b = bs >> 11, s = bs & 2047;
    outc[e2] = coor[(b * N_ + indx[s]) * 3 + c];
  } else {
    int p = e - 81920;                       // 0..65535 SoA pack
    const int b = p >> 13, i = p & 8191;
    const float* src = coor + (size_t)p * 3;
    float* dst = soa + b * 24576;
    dst[i]         = src[0];
    dst[8192 + i]  = src[1];
    dst[16384 + i] = src[2];
  }
}

// ---------------- KNN: threshold-select, one query per 256-thread block -------
// Output = SET of 32 smallest keys (dist_bits<<32 | idx); order arbitrary
// (downstream max/mean/var are permutation-invariant over K).
// dist[macro 0..3] in registers, macro 4..7 in LDS; NO recompute.
__global__ __launch_bounds__(256, 8) void kknn(const float* __restrict__ soa,
                                               const int* __restrict__ indx,
                                               int* __restrict__ knn) {
  __shared__ __align__(16) float4 sdist4[4 * 256];  // 16KB: dist[it-4][tid] x4
  __shared__ float sTw[8];                    // per-half-wave 4th-smallest min
  __shared__ unsigned long long cands[192];
  __shared__ int ccnt;

  const int gid = blockIdx.x;
  const int b = gid >> 11, s = gid & 2047;
  const int tid = threadIdx.x;
  const int w = tid >> 6, lane = tid & 63;
  const int hl = lane & 31;                   // half-wave lane
  const float* Xb = soa + b * 24576;
  const float* Yb = Xb + 8192;
  const float* Zb = Xb + 16384;
  const int qi = indx[s];
  const float qx = Xb[qi], qy = Yb[qi], qz = Zb[qi];
  const f32x2 nqx = {-qx, -qx}, nqy = {-qy, -qy}, nqz = {-qz, -qz};

  // pass 1: 8 macro-iters x 4 adjacent points per lane (packed fp32 math).
  // Per component: d = ((dx*dx + dy*dy) + dz*dz), dx = cx + (-qx) -- bit-exact
  // vs scalar __fsub_rn/__fmul_rn/__fadd_rn.
  f32x2 rd[8];                                // macro 0..3 -> 16 dists in regs
  float dmA = 3.4e38f, dmB = 3.4e38f;
#pragma unroll
  for (int it = 0; it < 8; ++it) {
    const int ofs = (it << 10) + (tid << 2);
    union { float4 f4; f32x2 h[2]; } X, Y, Z;
    X.f4 = *(const float4*)(Xb + ofs);
    Y.f4 = *(const float4*)(Yb + ofs);
    Z.f4 = *(const float4*)(Zb + ofs);
    const f32x2 dxl = pk_add(X.h[0], nqx), dyl = pk_add(Y.h[0], nqy),
                dzl = pk_add(Z.h[0], nqz);
    const f32x2 dxh = pk_add(X.h[1], nqx), dyh = pk_add(Y.h[1], nqy),
                dzh = pk_add(Z.h[1], nqz);
    const f32x2 sl =
        pk_add(pk_add(pk_mul(dxl, dxl), pk_mul(dyl, dyl)), pk_mul(dzl, dzl));
    const f32x2 sh =
        pk_add(pk_add(pk_mul(dxh, dxh), pk_mul(dyh, dyh)), pk_mul(dzh, dzh));
    dmA = fminf(fminf(sl.x, sl.y), dmA);      // v_min3_f32
    dmB = fminf(fminf(sh.x, sh.y), dmB);
    if (it < 4) {
      rd[it * 2] = sl;
      rd[it * 2 + 1] = sh;
    } else {
      union { float4 f4; f32x2 h[2]; } st;
      st.h[0] = sl;
      st.h[1] = sh;
      sdist4[((it - 4) << 8) + tid] = st.f4;   // one ds_write_b128
    }
  }
  float dmin = fminf(dmA, dmB);
  if (tid == 0) ccnt = 0;
  if (tid < 192) cands[tid] = ~0ULL;          // sentinel (> any real key)

  // pass 2: per-HALF-WAVE ascending bitonic sort (32 elements, 15 stages;
  // direction from hl=lane&31 so both halves sort ascending). Lane hl==3
  // holds the half-wave's 4th-smallest thread-min. T = max over the 8
  // half-waves. Each half-wave has >=4 thread-mins <= T -> >=4 distinct
  // elements <= T -> >=32 total -> T >= d32.
  float v = dmin;
#pragma unroll
  for (int k = 2; k <= 32; k <<= 1) {
#pragma unroll
    for (int j = k >> 1; j >= 1; j >>= 1) {
      const float o = __shfl_xor(v, j, 64);
      const bool dirAsc = ((hl & k) == 0);
      const bool lower = ((hl & j) == 0);
      const float lo = fminf(v, o), hi = fmaxf(v, o);
      v = (dirAsc == lower) ? lo : hi;
    }
  }
  if (hl == 3) sTw[(w << 1) + (lane >> 5)] = v;
  __syncthreads();
  const float T =
      fmaxf(fmaxf(fmaxf(sTw[0], sTw[1]), fmaxf(sTw[2], sTw[3])),
            fmaxf(fmaxf(sTw[4], sTw[5]), fmaxf(sTw[6], sTw[7])));

  // pass 3: compact candidates (dist <= T) from regs + LDS; E~55-70, cap 192.
  // Sparse predicate -> per-lane atomicAdd is cheaper than wave aggregation
  // (R19 post-mortem).
#pragma unroll
  for (int t = 0; t < 8; ++t) {
    const int p0 = ((t >> 1) << 10) + (tid << 2) + ((t & 1) << 1);
    const float d0 = rd[t].x, d1 = rd[t].y;
    if (d0 <= T) {
      const int pos = atomicAdd(&ccnt, 1);
      if (pos < 192)
        cands[pos] = ((unsigned long long)__float_as_uint(d0) << 32) |
                     (unsigned int)p0;
    }
    if (d1 <= T) {
      const int pos = atomicAdd(&ccnt, 1);
      if (pos < 192)
        cands[pos] = ((unsigned long long)__float_as_uint(d1) << 32) |
                     (unsigned int)(p0 + 1);
    }
  }
#pragma unroll
  for (int it = 4; it < 8; ++it) {
    const float4 d4 = sdist4[((it - 4) << 8) + tid];   // one ds_read_b128
    const int p0 = (it << 10) + (tid << 2);
    const float dd[4] = {d4.x, d4.y, d4.z, d4.w};
#pragma unroll
    for (int j = 0; j < 4; ++j) {
      if (dd[j] <= T) {
        const int pos = atomicAdd(&ccnt, 1);
        if (pos < 192)
          cands[pos] = ((unsigned long long)__float_as_uint(dd[j]) << 32) |
                       (unsigned int)(p0 + j);
      }
    }
  }
  __syncthreads();

  // pass 4: exact top-32 of E candidates by rank-count. Keys distinct (idx in
  // low bits) -> ranks 0..E-1 a permutation; rank<32 writes. Scan padded to
  // Ep=(E+3)&~3 with unroll-4: slots [E,192) hold ~0ULL sentinels which never
  // compare < key (real keys < ~0ULL), so rank is exact while the broadcast
  // ds_reads batch 4 per waitcnt instead of dependent singles.
  const int E = min(ccnt, 192);               // E >= 32 guaranteed
  if (tid < E) {
    const unsigned long long key = cands[tid];
    int rank = 0;
    const int Ep = (E + 3) & ~3;
#pragma unroll 4
    for (int j = 0; j < Ep; ++j) rank += (cands[j] < key) ? 1 : 0;
    if (rank < 32) knn[gid * 32 + rank] = (int)(unsigned int)key;
  }
}

// ---------------- phase kernels: MFMA fused GEMMs ----------------------------
// Wave w owns cols 32w..32w+31. Per lane: m = lane&31 (A row / D col), q2 = lane>>5.
// A layout: A[m=lane&31][k=q2*8+j]; B layout: B^T[n=lane&31][k=q2*8+j];
// C/D layout: col=lane&31, row=(reg&3)+8*(reg>>2)+4*q2  [m74/m101-verified].
// Layer-1 is K=128: A = [sx bf16 (k<64) | d bf16 (k>=64)], B = full w1.
// XCD map: batch = blockIdx&7 (one 2MB x-slice per XCD L2).
// PAIR pipeline (R25): two groups per barrier segment, 4-deep dls/sxb
// rotation, pair-issued register prefetch; lgkm-only barriers (vmcnt never
// drained -> prefetch loads fly across barriers).
template <int PHASE>
__global__ __launch_bounds__(256, 2) void kphase(
    const float* __restrict__ x, const int* __restrict__ indx,
    const int* __restrict__ knn, const float* __restrict__ b1,
    const unsigned short* __restrict__ w1b, const unsigned short* __restrict__ w2b,
    const float* __restrict__ b2, const float* __restrict__ st1,
    float* __restrict__ part, float* __restrict__ mout) {
  __shared__ __align__(16) unsigned short sxb[4][80];          // bf16 sx x4
  __shared__ __align__(16) unsigned short dls[4][32 * 68 + 8]; // d rows x4
  __shared__ __align__(16) unsigned short h1[PHASE == 2 ? 2 * 32 * 136 : 8];

  const int tid = threadIdx.x;
  const int w = tid >> 6;
  const int lane = tid & 63;
  const int m = lane & 31, q2 = lane >> 5;
  const int col = (w << 5) + m;              // output channel of this lane
  const int r8 = tid >> 3, c8 = (tid & 7) * 8;  // staging map: row, col-base

  const int bb = blockIdx.x & 7;             // batch == target XCD
  const int jj = blockIdx.x >> 3;            // 0..127 chunk within batch
  const float* xb = x + (size_t)bb * (N_ * 64);
  const int gidbase = (bb << 11) + jj * GPB_;
  const int sbase = jj * GPB_;

  // group-invariant operands in registers
  bf8 bf1[8];
#pragma unroll
  for (int t = 0; t < 8; ++t)
    bf1[t] = *(const bf8*)&w1b[col * 128 + t * 16 + q2 * 8];
  bf8 bf2[8];
  float s1 = 0.f, t1 = 0.f, b2v = 0.f;
  if constexpr (PHASE == 2) {
#pragma unroll
    for (int t = 0; t < 8; ++t)
      bf2[t] = *(const bf8*)&w2b[col * 128 + t * 16 + q2 * 8];
    s1 = st1[col];
    t1 = st1[128 + col];
    b2v = b2[col];
  }
  (void)w2b; (void)b2; (void)st1; (void)mout;
  const float b1c = b1[col];

  float sum = 0.f, ssq = 0.f;

  // prologue: load pair (g=0, g=1) rows into regs; indices for pair (2,3)
  float4 caA, ccA, gaA, gcA, caB, ccB, gaB, gcB;
  {
    const int idxA = indx[sbase];
    const int idxB = indx[sbase + 1];
    const int nbrA = knn[(size_t)gidbase * 32 + r8];
    const int nbrB = knn[(size_t)(gidbase + 1) * 32 + r8];
    const float* cA = xb + (size_t)idxA * 64;
    caA = *(const float4*)(cA + c8);
    ccA = *(const float4*)(cA + c8 + 4);
    const float* gA = xb + (size_t)nbrA * 64;
    gaA = *(const float4*)(gA + c8);
    gcA = *(const float4*)(gA + c8 + 4);
    const float* cB = xb + (size_t)idxB * 64;
    caB = *(const float4*)(cB + c8);
    ccB = *(const float4*)(cB + c8 + 4);
    const float* gB = xb + (size_t)nbrB * 64;
    gaB = *(const float4*)(gB + c8);
    gcB = *(const float4*)(gB + c8 + 4);
  }
  int idxA2 = (GPB_ > 2) ? indx[sbase + 2] : 0;
  int idxB2 = (GPB_ > 3) ? indx[sbase + 3] : 0;
  int nbrA2 = (GPB_ > 2) ? knn[(size_t)(gidbase + 2) * 32 + r8] : 0;
  int nbrB2 = (GPB_ > 3) ? knn[(size_t)(gidbase + 3) * 32 + r8] : 0;

#pragma unroll 1
  for (int g = 0; g < GPB_; g += 2) {
    const int gid = gidbase + g;
    const int p0 = g & 3, p1 = (g + 1) & 3;

    // issue prefetch for pair (g+2, g+3) FIRST (flies across the barriers)
    float4 caA_n = caA, ccA_n = ccA, gaA_n = gaA, gcA_n = gcA;
    float4 caB_n = caB, ccB_n = ccB, gaB_n = gaB, gcB_n = gcB;
    if (g + 2 < GPB_) {
      const float* cA = xb + (size_t)idxA2 * 64;
      caA_n = *(const float4*)(cA + c8);
      ccA_n = *(const float4*)(cA + c8 + 4);
      const float* gA = xb + (size_t)nbrA2 * 64;
      gaA_n = *(const float4*)(gA + c8);
      gcA_n = *(const float4*)(gA + c8 + 4);
      const float* cB = xb + (size_t)idxB2 * 64;
      caB_n = *(const float4*)(cB + c8);
      ccB_n = *(const float4*)(cB + c8 + 4);
      const float* gB = xb + (size_t)nbrB2 * 64;
      gaB_n = *(const float4*)(gB + c8);
      gcB_n = *(const float4*)(gB + c8 + 4);
    }
    if (g + 4 < GPB_) {                      // indices for pair (g+4, g+5)
      nbrA2 = knn[(size_t)(gid + 4) * 32 + r8];
      nbrB2 = knn[(size_t)(gid + 5) * 32 + r8];
      idxA2 = indx[sbase + g + 4];
      idxB2 = indx[sbase + g + 5];
    }

    // stage BOTH groups: d = x[nbr] - sx as bf16 (regs loaded last iter)
    {
      uint2 lo, hi;
      lo.x = bfpair(gaA.x - caA.x, gaA.y - caA.y);
      lo.y = bfpair(gaA.z - caA.z, gaA.w - caA.w);
      hi.x = bfpair(gcA.x - ccA.x, gcA.y - ccA.y);
      hi.y = bfpair(gcA.z - ccA.z, gcA.w - ccA.w);
      *(uint2*)&dls[p0][r8 * 68 + c8] = lo;
      *(uint2*)&dls[p0][r8 * 68 + c8 + 4] = hi;
      lo.x = bfpair(gaB.x - caB.x, gaB.y - caB.y);
      lo.y = bfpair(gaB.z - caB.z, gaB.w - caB.w);
      hi.x = bfpair(gcB.x - ccB.x, gcB.y - ccB.y);
      hi.y = bfpair(gcB.z - ccB.z, gcB.w - ccB.w);
      *(uint2*)&dls[p1][r8 * 68 + c8] = lo;
      *(uint2*)&dls[p1][r8 * 68 + c8 + 4] = hi;
    }
    if (tid < 8) {                           // tid<8: c8==tid*8 -> full sx row
      uint2 lo, hi;
      lo.x = bfpair(caA.x, caA.y);
      lo.y = bfpair(caA.z, caA.w);
      hi.x = bfpair(ccA.x, ccA.y);
      hi.y = bfpair(ccA.z, ccA.w);
      *(uint2*)&sxb[p0][tid * 8] = lo;
      *(uint2*)&sxb[p0][tid * 8 + 4] = hi;
      lo.x = bfpair(caB.x, caB.y);
      lo.y = bfpair(caB.z, caB.w);
      hi.x = bfpair(ccB.x, ccB.y);
      hi.y = bfpair(ccB.z, ccB.w);
      *(uint2*)&sxb[p1][tid * 8] = lo;
      *(uint2*)&sxb[p1][tid * 8 + 4] = hi;
    }
    // LDS-visibility-only barrier: vmcnt NOT drained
    asm volatile("s_waitcnt lgkmcnt(0)" ::: "memory");
    __builtin_amdgcn_s_barrier();

    // ---- GEMM1 for both pair members (16 MFMA in this segment) ----
#pragma unroll
    for (int mem = 0; mem < 2; ++mem) {
      const int pb = mem == 0 ? p0 : p1;
      bf8 af[8];
#pragma unroll
      for (int t = 0; t < 4; ++t) {
        union { bf8 v; uint2 u[2]; } fa;
        fa.u[0] = *(const uint2*)&sxb[pb][t * 16 + q2 * 8];
        fa.u[1] = *(const uint2*)&sxb[pb][t * 16 + q2 * 8 + 4];
        af[t] = fa.v;
      }
#pragma unroll
      for (int t = 0; t < 4; ++t) {
        union { bf8 v; uint2 u[2]; } fa;
        fa.u[0] = *(const uint2*)&dls[pb][m * 68 + t * 16 + q2 * 8];
        fa.u[1] = *(const uint2*)&dls[pb][m * 68 + t * 16 + q2 * 8 + 4];
        af[4 + t] = fa.v;
      }
      f32x16 acc;
#pragma unroll
      for (int r = 0; r < 16; ++r) acc[r] = b1c;
#pragma unroll
      for (int t = 0; t < 8; ++t)
        acc = __builtin_amdgcn_mfma_f32_32x32x16_bf16(af[t], bf1[t], acc, 0, 0, 0);

      if constexpr (PHASE == 1) {
#pragma unroll
        for (int r = 0; r < 16; ++r) {
          const float v = acc[r];
          sum += v;
          ssq = fmaf(v, v, ssq);
        }
      } else {
        const int hp = mem * (32 * 136);     // bn1+relu -> h1[mem]
#pragma unroll
        for (int r = 0; r < 16; ++r) {
          const float hv = fmaxf(0.f, fmaf(acc[r], s1, t1));
          const int row = (r & 3) + ((r >> 2) << 3) + (q2 << 2);
          h1[hp + row * 136 + col] = (unsigned short)bf1u(hv);
        }
      }
    }

    if constexpr (PHASE == 2) {
      asm volatile("s_waitcnt lgkmcnt(0)" ::: "memory");
      __builtin_amdgcn_s_barrier();          // h1[0],h1[1] ready (lgkm only)
#pragma unroll
      for (int mem = 0; mem < 2; ++mem) {
        const int hp = mem * (32 * 136);
        f32x16 acc2;
#pragma unroll
        for (int r = 0; r < 16; ++r) acc2[r] = b2v;
#pragma unroll
        for (int t = 0; t < 8; ++t) {
          const bf8 a2 = *(const bf8*)&h1[hp + m * 136 + t * 16 + q2 * 8];
          acc2 = __builtin_amdgcn_mfma_f32_32x32x16_bf16(a2, bf2[t], acc2, 0, 0, 0);
        }
        float mx = -1e30f;
#pragma unroll
        for (int r = 0; r < 16; ++r) {
          const float v = acc2[r];
          sum += v;
          ssq = fmaf(v, v, ssq);
          mx = fmaxf(mx, v);
        }
        mx = fmaxf(mx, __shfl_xor(mx, 32, 64));
        if (lane < 32) mout[(size_t)(gid + mem) * 128 + col] = mx;
      }
    }

    // rotate prefetched pair regs
    caA = caA_n; ccA = ccA_n; gaA = gaA_n; gcA = gcA_n;
    caB = caB_n; ccB = ccB_n; gaB = gaB_n; gcB = gcB_n;
  }

  // channel partials: each channel owned by exactly one wave
  sum += __shfl_xor(sum, 32, 64);
  ssq += __shfl_xor(ssq, 32, 64);
  if (lane < 32) {
    part[blockIdx.x * 256 + col] = sum;
    part[blockIdx.x * 256 + 128 + col] = ssq;
  }
}

// ---------------- stats reduce stage 1: 64 blocks, f64 partial sums ----------
__global__ __launch_bounds__(256) void kred1(const float* __restrict__ part,
                                             double* __restrict__ dbuf) {
  const int blk = blockIdx.x;                // 0..63: rows 16*blk..16*blk+15
  const int c = threadIdx.x;                 // 0..255 (128 sums | 128 ssqs)
  const float* p = part + (size_t)blk * 16 * 256 + c;
  double acc = 0.0;
#pragma unroll
  for (int r = 0; r < 16; ++r) acc += (double)p[r * 256];
  dbuf[blk * 256 + c] = acc;
}

// ---------------- stats reduce stage 2: finalize scale/shift -----------------
__global__ __launch_bounds__(256) void kred2(const double* __restrict__ dbuf,
                                             const float* __restrict__ gam,
                                             const float* __restrict__ bet,
                                             float* __restrict__ st) {
  __shared__ double sS[256];
  const int c = threadIdx.x;
  double acc = 0.0;
#pragma unroll 8
  for (int i = 0; i < 64; ++i) acc += dbuf[i * 256 + c];
  sS[c] = acc;
  __syncthreads();
  if (c < 128) {
    const double Sv = sS[c], SSv = sS[128 + c];
    const double cnt = 524288.0;             // B*S*K
    const double mean = Sv / cnt;
    const double var = SSv / cnt - mean * mean;
    const double scale = (double)gam[c] / sqrt(var + 1e-5);
    st[c] = (float)scale;
    st[128 + c] = (float)((double)bet[c] - mean * scale);
  }
}

// ---------------- final: out = relu(scale2 * max_k(y2) + shift2) -------------
__global__ __launch_bounds__(256) void kout(const float* __restrict__ m,
                                            const float* __restrict__ st2,
                                            float* __restrict__ out) {
  const int e4 = blockIdx.x * 256 + threadIdx.x;  // 524288 float4s
  const int o0 = (e4 & 31) * 4;
  const float4 v = ((const float4*)m)[e4];
  const float4 sc = *(const float4*)&st2[o0];
  const float4 sh = *(const float4*)&st2[128 + o0];
  float4 r;
  r.x = fmaxf(0.f, fmaf(v.x, sc.x, sh.x));
  r.y = fmaxf(0.f, fmaf(v.y, sc.y, sh.y));
  r.z = fmaxf(0.f, fmaf(v.z, sc.z, sh.z));
  r.w = fmaxf(0.f, fmaf(v.w, sc.w, sh.w));
  ((float4*)out)[e4] = r;
}

extern "C" void kernel_launch(void* const* d_in, const int* in_sizes, int n_in,
                              void* d_out, int out_size, void* d_ws, size_t ws_size,
                              hipStream_t stream) {
  (void)in_sizes; (void)n_in; (void)out_size; (void)ws_size;
  const float* x    = (const float*)d_in[0];
  const float* coor = (const float*)d_in[1];
  const int*   indx = (const int*)d_in[2];
  const float* w1   = (const float*)d_in[3];
  const float* b1   = (const float*)d_in[4];
  const float* g1   = (const float*)d_in[5];
  const float* be1  = (const float*)d_in[6];
  const float* w2   = (const float*)d_in[7];
  const float* b2   = (const float*)d_in[8];
  const float* g2   = (const float*)d_in[9];
  const float* be2  = (const float*)d_in[10];
  float* out = (float*)d_out;

  char* ws = (char*)d_ws;
  int*            knn   = (int*)(ws + 0);
  float*          mbuf  = (float*)(ws + 2097152);
  float*          part1 = (float*)(ws + 10485760);
  float*          soa   = (float*)(ws + 10485760); // aliases part1 (disjoint lifetime)
  float*          part2 = (float*)(ws + 12582912);
  unsigned short* w1b   = (unsigned short*)(ws + 14680064);
  unsigned short* w2b   = (unsigned short*)(ws + 14712832);
  float*          st1   = (float*)(ws + 14745600);
  float*          st2   = (float*)(ws + 14746624);
  double*         dbuf  = (double*)(ws + 14747648);

  float* outc = out + 2097152;   // sampled_coor region of d_out

  kprep<<<576, 256, 0, stream>>>(w1, w2, coor, indx, w1b, w2b, outc, soa);
  kknn<<<16384, 256, 0, stream>>>(soa, indx, knn);
  kphase<1><<<1024, 256, 0, stream>>>(x, indx, knn, b1, w1b, w2b, b2, nullptr,
                                      part1, nullptr);
  kred1<<<64, 256, 0, stream>>>(part1, dbuf);
  kred2<<<1, 256, 0, stream>>>(dbuf, g1, be1, st1);
  kphase<2><<<1024, 256, 0, stream>>>(x, indx, knn, b1, w1b, w2b, b2, st1,
                                      part2, mbuf);
  kred1<<<64, 256, 0, stream>>>(part2, dbuf);
  kred2<<<1, 256, 0, stream>>>(dbuf, g2, be2, st2);
  kout<<<2048, 256, 0, stream>>>(mbuf, st2, out);
}